// Round 2
// baseline (1158.411 us; speedup 1.0000x reference)
//
#include <hip/hip_runtime.h>
#include <stdint.h>

// Problem constants (match reference)
#define N_NODES  50000
#define N_EDGES  800000
#define D        256
#define D_OUT    16
#define N_GRAPHS 128

// 1 = JAX jax_threefry_partitionable=True (default since jax 0.4.30):
//     bits32(i) = fold of threefry2x32((0,42), (hi(i), lo(i))) ; fold = o0 ^ o1
// 0 = legacy split-half counter scheme
#define PARTITIONABLE 1

// Workspace layout (in floats)
#define DINV_OFF  0
#define H_OFF     65536
#define AGG_OFF   (H_OFF + N_NODES * D)
#define SUMS_OFF  (AGG_OFF + N_NODES * D)
#define CNT_OFF   (SUMS_OFF + N_GRAPHS * D)

__device__ __forceinline__ uint32_t rotl32(uint32_t x, int d) {
    return (x << d) | (x >> (32 - d));
}

// Threefry-2x32, 20 rounds, exactly as in jax._src.prng
__device__ __forceinline__ void threefry2x32(uint32_t k0, uint32_t k1,
                                             uint32_t c0, uint32_t c1,
                                             uint32_t& o0, uint32_t& o1) {
    uint32_t ks2 = k0 ^ k1 ^ 0x1BD11BDAu;
    uint32_t x0 = c0 + k0, x1 = c1 + k1;
    // group 1 (rot 13,15,26,6)
    x0 += x1; x1 = rotl32(x1, 13); x1 ^= x0;
    x0 += x1; x1 = rotl32(x1, 15); x1 ^= x0;
    x0 += x1; x1 = rotl32(x1, 26); x1 ^= x0;
    x0 += x1; x1 = rotl32(x1, 6);  x1 ^= x0;
    x0 += k1; x1 += ks2 + 1u;
    // group 2 (rot 17,29,16,24)
    x0 += x1; x1 = rotl32(x1, 17); x1 ^= x0;
    x0 += x1; x1 = rotl32(x1, 29); x1 ^= x0;
    x0 += x1; x1 = rotl32(x1, 16); x1 ^= x0;
    x0 += x1; x1 = rotl32(x1, 24); x1 ^= x0;
    x0 += ks2; x1 += k0 + 2u;
    // group 3
    x0 += x1; x1 = rotl32(x1, 13); x1 ^= x0;
    x0 += x1; x1 = rotl32(x1, 15); x1 ^= x0;
    x0 += x1; x1 = rotl32(x1, 26); x1 ^= x0;
    x0 += x1; x1 = rotl32(x1, 6);  x1 ^= x0;
    x0 += k0; x1 += k1 + 3u;
    // group 4
    x0 += x1; x1 = rotl32(x1, 17); x1 ^= x0;
    x0 += x1; x1 = rotl32(x1, 29); x1 ^= x0;
    x0 += x1; x1 = rotl32(x1, 16); x1 ^= x0;
    x0 += x1; x1 = rotl32(x1, 24); x1 ^= x0;
    x0 += k1; x1 += ks2 + 4u;
    // group 5
    x0 += x1; x1 = rotl32(x1, 13); x1 ^= x0;
    x0 += x1; x1 = rotl32(x1, 15); x1 ^= x0;
    x0 += x1; x1 = rotl32(x1, 26); x1 ^= x0;
    x0 += x1; x1 = rotl32(x1, 6);  x1 ^= x0;
    x0 += ks2; x1 += k0 + 5u;
    o0 = x0; o1 = x1;
}

// keep iff uniform(i) < 0.5 iff top bit of random bits == 0
__device__ __forceinline__ bool dropout_keep(uint32_t i) {
    uint32_t o0, o1, bits;
#if PARTITIONABLE
    threefry2x32(0u, 42u, 0u, i, o0, o1);
    bits = o0 ^ o1;   // sub-64-bit path folds both output words
#else
    const uint32_t HALF = (uint32_t)(N_NODES * D / 2);
    if (i < HALF) { threefry2x32(0u, 42u, i, i + HALF, o0, o1); bits = o0; }
    else          { threefry2x32(0u, 42u, i - HALF, i, o0, o1); bits = o1; }
#endif
    return (bits & 0x80000000u) == 0u;
}

__global__ __launch_bounds__(256) void k_deg_init(float* deg) {
    int i = blockIdx.x * 256 + threadIdx.x;
    if (i < N_NODES) deg[i] = 1.0f;   // self-loop weight
}

__global__ __launch_bounds__(256) void k_deg_edges(const int* __restrict__ ei,
                                                   const float* __restrict__ ew,
                                                   float* __restrict__ deg) {
    int e = blockIdx.x * 256 + threadIdx.x;
    if (e < N_EDGES) atomicAdd(&deg[ei[N_EDGES + e]], ew[e]);  // col = target
}

__global__ __launch_bounds__(256) void k_dinv(float* deg) {
    int i = blockIdx.x * 256 + threadIdx.x;
    if (i < N_NODES) {
        float d = deg[i];
        deg[i] = (d > 0.0f) ? rsqrtf(d) : 0.0f;
    }
}

// h = x @ W1   (no bias; bias added post-aggregation per reference)
// 16 nodes per block, thread t computes h[node][t] for 16 nodes.
__global__ __launch_bounds__(256) void k_gemm(const float* __restrict__ x,
                                              const float* __restrict__ W,
                                              float* __restrict__ h) {
    __shared__ float4 xs[16][64];
    int t = threadIdx.x;
    int node0 = blockIdx.x * 16;
    const float4* xv = (const float4*)x;
    for (int i = t; i < 16 * 64; i += 256) {
        int m = i >> 6, c = i & 63;
        xs[m][c] = xv[(size_t)(node0 + m) * 64 + c];
    }
    __syncthreads();
    float acc[16];
#pragma unroll
    for (int m = 0; m < 16; m++) acc[m] = 0.0f;
    for (int kc = 0; kc < 64; kc++) {
        float w0 = W[(kc * 4 + 0) * D + t];
        float w1 = W[(kc * 4 + 1) * D + t];
        float w2 = W[(kc * 4 + 2) * D + t];
        float w3 = W[(kc * 4 + 3) * D + t];
#pragma unroll
        for (int m = 0; m < 16; m++) {
            float4 xm = xs[m][kc];
            acc[m] = fmaf(xm.x, w0, acc[m]);
            acc[m] = fmaf(xm.y, w1, acc[m]);
            acc[m] = fmaf(xm.z, w2, acc[m]);
            acc[m] = fmaf(xm.w, w3, acc[m]);
        }
    }
#pragma unroll
    for (int m = 0; m < 16; m++)
        h[(size_t)(node0 + m) * D + t] = acc[m];
}

// One block per edge: agg[col] += norm * h[row]
__global__ __launch_bounds__(256) void k_scatter(const int* __restrict__ ei,
                                                 const float* __restrict__ ew,
                                                 const float* __restrict__ dinv,
                                                 const float* __restrict__ h,
                                                 float* __restrict__ agg) {
    int e = blockIdx.x;
    int r = ei[e];
    int c = ei[N_EDGES + e];
    float nrm = dinv[r] * ew[e] * dinv[c];
    int t = threadIdx.x;
    atomicAdd(&agg[(size_t)c * D + t], nrm * h[(size_t)r * D + t]);
}

// Per node: + self-loop + bias, ReLU, dropout, pool-sum atomics
__global__ __launch_bounds__(256) void k_post(const float* __restrict__ agg,
                                              const float* __restrict__ h,
                                              const float* __restrict__ dinv,
                                              const float* __restrict__ b1,
                                              const int* __restrict__ gidx,
                                              float* __restrict__ sums,
                                              float* __restrict__ cnt) {
    int n = blockIdx.x;
    int t = threadIdx.x;
    float di = dinv[n];
    float v = agg[(size_t)n * D + t] + di * di * h[(size_t)n * D + t] + b1[t];
    v = fmaxf(v, 0.0f);                       // ReLU
    uint32_t i = (uint32_t)(n * D + t);
    v = dropout_keep(i) ? v * 2.0f : 0.0f;    // dropout p=0.5, scale 1/(1-p)
    int g = gidx[n];
    atomicAdd(&sums[g * D + t], v);
    if (t == 0) atomicAdd(&cnt[g], 1.0f);
}

// Per graph: pooled = sums/max(cnt,1);  out = pooled @ fc_W + fc_b
__global__ __launch_bounds__(256) void k_final(const float* __restrict__ sums,
                                               const float* __restrict__ cnt,
                                               const float* __restrict__ fcW,
                                               const float* __restrict__ fcb,
                                               float* __restrict__ out) {
    __shared__ float p[D];
    int g = blockIdx.x, t = threadIdx.x;
    float c = fmaxf(cnt[g], 1.0f);
    p[t] = sums[g * D + t] / c;
    __syncthreads();
    if (t < D_OUT) {
        float acc = fcb[t];
        for (int k = 0; k < D; k++)
            acc = fmaf(p[k], fcW[k * D_OUT + t], acc);
        out[g * D_OUT + t] = acc;
    }
}

extern "C" void kernel_launch(void* const* d_in, const int* in_sizes, int n_in,
                              void* d_out, int out_size, void* d_ws, size_t ws_size,
                              hipStream_t stream) {
    const float* x   = (const float*)d_in[0];
    const int*   ei  = (const int*)d_in[1];
    const float* ew  = (const float*)d_in[2];
    const int*   gix = (const int*)d_in[3];
    const float* W1  = (const float*)d_in[4];
    const float* b1  = (const float*)d_in[5];
    const float* fcW = (const float*)d_in[6];
    const float* fcb = (const float*)d_in[7];
    float* out = (float*)d_out;

    float* ws   = (float*)d_ws;
    float* dinv = ws + DINV_OFF;
    float* h    = ws + H_OFF;
    float* agg  = ws + AGG_OFF;
    float* sums = ws + SUMS_OFF;
    float* cnt  = ws + CNT_OFF;

    // Re-zero accumulators every call (replays do not re-poison ws)
    hipMemsetAsync(agg, 0, (size_t)N_NODES * D * sizeof(float), stream);
    hipMemsetAsync(sums, 0, (size_t)(N_GRAPHS * D + N_GRAPHS) * sizeof(float), stream);

    k_deg_init<<<(N_NODES + 255) / 256, 256, 0, stream>>>(dinv);
    k_deg_edges<<<(N_EDGES + 255) / 256, 256, 0, stream>>>(ei, ew, dinv);
    k_dinv<<<(N_NODES + 255) / 256, 256, 0, stream>>>(dinv);
    k_gemm<<<N_NODES / 16, 256, 0, stream>>>(x, W1, h);
    k_scatter<<<N_EDGES, 256, 0, stream>>>(ei, ew, dinv, h, agg);
    k_post<<<N_NODES, 256, 0, stream>>>(agg, h, dinv, b1, gix, sums, cnt);
    k_final<<<N_GRAPHS, 256, 0, stream>>>(sums, cnt, fcW, fcb, out);
}

// Round 3
// 835.665 us; speedup vs baseline: 1.3862x; 1.3862x over previous
//
#include <hip/hip_runtime.h>
#include <stdint.h>

// Problem constants (match reference)
#define N_NODES  50000
#define N_EDGES  800000
#define D        256
#define D_OUT    16
#define N_GRAPHS 128

// JAX jax_threefry_partitionable=True: bits32(i) = fold(threefry2x32((0,42),(0,i))),
// fold = o0 ^ o1; keep iff top bit == 0.  (verified round 2, absmax 0.0)

// ---------------- workspace layout (floats) ----------------
// dinv   : 65536
// h      : N_NODES*D = 12,800,000
// rows   : 800,000 (int)
// wn     : 800,000 (float)
// start  : 65,536 (int)   (needs N_NODES+1)
// cursor : 65,536 (int)
// sums   : N_GRAPHS*D = 32,768
// cnt    : 128
// total ~14.56 M floats = 58.3 MB  (< round-2's 103 MB, fits)

__device__ __forceinline__ uint32_t rotl32(uint32_t x, int d) {
    return (x << d) | (x >> (32 - d));
}

__device__ __forceinline__ void threefry2x32(uint32_t k0, uint32_t k1,
                                             uint32_t c0, uint32_t c1,
                                             uint32_t& o0, uint32_t& o1) {
    uint32_t ks2 = k0 ^ k1 ^ 0x1BD11BDAu;
    uint32_t x0 = c0 + k0, x1 = c1 + k1;
    x0 += x1; x1 = rotl32(x1, 13); x1 ^= x0;
    x0 += x1; x1 = rotl32(x1, 15); x1 ^= x0;
    x0 += x1; x1 = rotl32(x1, 26); x1 ^= x0;
    x0 += x1; x1 = rotl32(x1, 6);  x1 ^= x0;
    x0 += k1; x1 += ks2 + 1u;
    x0 += x1; x1 = rotl32(x1, 17); x1 ^= x0;
    x0 += x1; x1 = rotl32(x1, 29); x1 ^= x0;
    x0 += x1; x1 = rotl32(x1, 16); x1 ^= x0;
    x0 += x1; x1 = rotl32(x1, 24); x1 ^= x0;
    x0 += ks2; x1 += k0 + 2u;
    x0 += x1; x1 = rotl32(x1, 13); x1 ^= x0;
    x0 += x1; x1 = rotl32(x1, 15); x1 ^= x0;
    x0 += x1; x1 = rotl32(x1, 26); x1 ^= x0;
    x0 += x1; x1 = rotl32(x1, 6);  x1 ^= x0;
    x0 += k0; x1 += k1 + 3u;
    x0 += x1; x1 = rotl32(x1, 17); x1 ^= x0;
    x0 += x1; x1 = rotl32(x1, 29); x1 ^= x0;
    x0 += x1; x1 = rotl32(x1, 16); x1 ^= x0;
    x0 += x1; x1 = rotl32(x1, 24); x1 ^= x0;
    x0 += k1; x1 += ks2 + 4u;
    x0 += x1; x1 = rotl32(x1, 13); x1 ^= x0;
    x0 += x1; x1 = rotl32(x1, 15); x1 ^= x0;
    x0 += x1; x1 = rotl32(x1, 26); x1 ^= x0;
    x0 += x1; x1 = rotl32(x1, 6);  x1 ^= x0;
    x0 += ks2; x1 += k0 + 5u;
    o0 = x0; o1 = x1;
}

__device__ __forceinline__ bool dropout_keep(uint32_t i) {
    uint32_t o0, o1;
    threefry2x32(0u, 42u, 0u, i, o0, o1);
    return ((o0 ^ o1) & 0x80000000u) == 0u;
}

__global__ __launch_bounds__(256) void k_deg_init(float* deg) {
    int i = blockIdx.x * 256 + threadIdx.x;
    if (i < N_NODES) deg[i] = 1.0f;   // self-loop weight
}

__global__ __launch_bounds__(256) void k_deg_edges(const int* __restrict__ ei,
                                                   const float* __restrict__ ew,
                                                   float* __restrict__ deg) {
    int e = blockIdx.x * 256 + threadIdx.x;
    if (e < N_EDGES) atomicAdd(&deg[ei[N_EDGES + e]], ew[e]);  // col = target
}

__global__ __launch_bounds__(256) void k_dinv(float* deg) {
    int i = blockIdx.x * 256 + threadIdx.x;
    if (i < N_NODES) {
        float d = deg[i];
        deg[i] = (d > 0.0f) ? rsqrtf(d) : 0.0f;
    }
}

// histogram of edge targets (start[] pre-zeroed by memset)
__global__ __launch_bounds__(256) void k_hist(const int* __restrict__ ei,
                                              int* __restrict__ start) {
    int e = blockIdx.x * 256 + threadIdx.x;
    if (e < N_EDGES) atomicAdd(&start[ei[N_EDGES + e]], 1);
}

// single-block exclusive scan of 50000 counts, in place; also copies to cursor
__global__ __launch_bounds__(1024) void k_scan(int* __restrict__ start,
                                               int* __restrict__ cursor) {
    __shared__ int part[1024];
    const int CH = 49;                     // 1024*49 = 50176 >= 50000
    int t = threadIdx.x;
    int lo = t * CH;
    int hi = lo + CH; if (hi > N_NODES) hi = N_NODES;
    int s = 0;
    for (int i = lo; i < hi; i++) s += start[i];
    part[t] = s;
    __syncthreads();
    for (int d = 1; d < 1024; d <<= 1) {
        int v = (t >= d) ? part[t - d] : 0;
        __syncthreads();
        part[t] += v;
        __syncthreads();
    }
    int run = part[t] - s;                 // exclusive base for this chunk
    for (int i = lo; i < hi; i++) {
        int c = start[i];
        start[i] = run;
        cursor[i] = run;
        run += c;
    }
    if (t == 1023) start[N_NODES] = run;   // lo>N: run == grand total
}

// scatter each edge's (row, norm) into its CSR slot
__global__ __launch_bounds__(256) void k_fill(const int* __restrict__ ei,
                                              const float* __restrict__ ew,
                                              const float* __restrict__ dinv,
                                              int* __restrict__ cursor,
                                              int* __restrict__ rows,
                                              float* __restrict__ wn) {
    int e = blockIdx.x * 256 + threadIdx.x;
    if (e < N_EDGES) {
        int r = ei[e];
        int c = ei[N_EDGES + e];
        int pos = atomicAdd(&cursor[c], 1);
        rows[pos] = r;
        wn[pos] = dinv[r] * ew[e] * dinv[c];
    }
}

// h = x @ W1  (16 nodes/block; thread t computes column t for all 16)
__global__ __launch_bounds__(256) void k_gemm(const float* __restrict__ x,
                                              const float* __restrict__ W,
                                              float* __restrict__ h) {
    __shared__ float4 xs[16][64];
    int t = threadIdx.x;
    int node0 = blockIdx.x * 16;
    const float4* xv = (const float4*)x;
    for (int i = t; i < 16 * 64; i += 256) {
        int m = i >> 6, c = i & 63;
        xs[m][c] = xv[(size_t)(node0 + m) * 64 + c];
    }
    __syncthreads();
    float acc[16];
#pragma unroll
    for (int m = 0; m < 16; m++) acc[m] = 0.0f;
    for (int kc = 0; kc < 64; kc++) {
        float w0 = W[(kc * 4 + 0) * D + t];
        float w1 = W[(kc * 4 + 1) * D + t];
        float w2 = W[(kc * 4 + 2) * D + t];
        float w3 = W[(kc * 4 + 3) * D + t];
#pragma unroll
        for (int m = 0; m < 16; m++) {
            float4 xm = xs[m][kc];
            acc[m] = fmaf(xm.x, w0, acc[m]);
            acc[m] = fmaf(xm.y, w1, acc[m]);
            acc[m] = fmaf(xm.z, w2, acc[m]);
            acc[m] = fmaf(xm.w, w3, acc[m]);
        }
    }
#pragma unroll
    for (int m = 0; m < 16; m++)
        h[(size_t)(node0 + m) * D + t] = acc[m];
}

// CSR aggregate + self-loop + bias + ReLU + dropout + pool atomics.
// One 64-lane wave per node (4 nodes per block), float4 per lane.
__global__ __launch_bounds__(256) void k_agg_post(const int* __restrict__ start,
                                                  const int* __restrict__ rows,
                                                  const float* __restrict__ wn,
                                                  const float* __restrict__ h,
                                                  const float* __restrict__ dinv,
                                                  const float* __restrict__ b1,
                                                  const int* __restrict__ gidx,
                                                  float* __restrict__ sums,
                                                  float* __restrict__ cnt) {
    int n = blockIdx.x * 4 + (threadIdx.x >> 6);
    int l = threadIdx.x & 63;
    const float4* h4 = (const float4*)h;
    int s = start[n], e = start[n + 1];
    float4 acc = make_float4(0.f, 0.f, 0.f, 0.f);
    for (int j = s; j < e; j++) {
        int r = rows[j];        // wave-uniform
        float w = wn[j];        // wave-uniform
        float4 hv = h4[(size_t)r * 64 + l];
        acc.x = fmaf(w, hv.x, acc.x);
        acc.y = fmaf(w, hv.y, acc.y);
        acc.z = fmaf(w, hv.z, acc.z);
        acc.w = fmaf(w, hv.w, acc.w);
    }
    float di = dinv[n];
    float sl = di * di;
    float4 hn = h4[(size_t)n * 64 + l];
    float4 bv = ((const float4*)b1)[l];
    float v0 = fmaxf(fmaf(sl, hn.x, acc.x) + bv.x, 0.f);
    float v1 = fmaxf(fmaf(sl, hn.y, acc.y) + bv.y, 0.f);
    float v2 = fmaxf(fmaf(sl, hn.z, acc.z) + bv.z, 0.f);
    float v3 = fmaxf(fmaf(sl, hn.w, acc.w) + bv.w, 0.f);
    uint32_t base = (uint32_t)n * D + (uint32_t)l * 4u;
    v0 = dropout_keep(base + 0u) ? v0 * 2.f : 0.f;
    v1 = dropout_keep(base + 1u) ? v1 * 2.f : 0.f;
    v2 = dropout_keep(base + 2u) ? v2 * 2.f : 0.f;
    v3 = dropout_keep(base + 3u) ? v3 * 2.f : 0.f;
    int g = gidx[n];
    float* sg = &sums[(size_t)g * D + (size_t)l * 4];
    atomicAdd(sg + 0, v0);
    atomicAdd(sg + 1, v1);
    atomicAdd(sg + 2, v2);
    atomicAdd(sg + 3, v3);
    if (l == 0) atomicAdd(&cnt[g], 1.0f);
}

// pooled = sums/max(cnt,1);  out = pooled @ fc_W + fc_b
__global__ __launch_bounds__(256) void k_final(const float* __restrict__ sums,
                                               const float* __restrict__ cnt,
                                               const float* __restrict__ fcW,
                                               const float* __restrict__ fcb,
                                               float* __restrict__ out) {
    __shared__ float p[D];
    int g = blockIdx.x, t = threadIdx.x;
    float c = fmaxf(cnt[g], 1.0f);
    p[t] = sums[g * D + t] / c;
    __syncthreads();
    if (t < D_OUT) {
        float acc = fcb[t];
        for (int k = 0; k < D; k++)
            acc = fmaf(p[k], fcW[k * D_OUT + t], acc);
        out[g * D_OUT + t] = acc;
    }
}

extern "C" void kernel_launch(void* const* d_in, const int* in_sizes, int n_in,
                              void* d_out, int out_size, void* d_ws, size_t ws_size,
                              hipStream_t stream) {
    const float* x   = (const float*)d_in[0];
    const int*   ei  = (const int*)d_in[1];
    const float* ew  = (const float*)d_in[2];
    const int*   gix = (const int*)d_in[3];
    const float* W1  = (const float*)d_in[4];
    const float* b1  = (const float*)d_in[5];
    const float* fcW = (const float*)d_in[6];
    const float* fcb = (const float*)d_in[7];
    float* out = (float*)d_out;

    float* ws     = (float*)d_ws;
    float* dinv   = ws;
    float* h      = ws + 65536;
    int*   rows   = (int*)(h + (size_t)N_NODES * D);
    float* wn     = (float*)(rows + N_EDGES);
    int*   start  = (int*)(wn + N_EDGES);
    int*   cursor = start + 65536;
    float* sums   = (float*)(cursor + 65536);
    float* cnt    = sums + N_GRAPHS * D;

    // per-call re-init (replays don't re-poison)
    hipMemsetAsync(start, 0, (N_NODES + 1) * sizeof(int), stream);
    hipMemsetAsync(sums, 0, (N_GRAPHS * D + N_GRAPHS) * sizeof(float), stream);

    k_deg_init<<<(N_NODES + 255) / 256, 256, 0, stream>>>(dinv);
    k_deg_edges<<<(N_EDGES + 255) / 256, 256, 0, stream>>>(ei, ew, dinv);
    k_dinv<<<(N_NODES + 255) / 256, 256, 0, stream>>>(dinv);
    k_hist<<<(N_EDGES + 255) / 256, 256, 0, stream>>>(ei, start);
    k_scan<<<1, 1024, 0, stream>>>(start, cursor);
    k_fill<<<(N_EDGES + 255) / 256, 256, 0, stream>>>(ei, ew, dinv, cursor, rows, wn);
    k_gemm<<<N_NODES / 16, 256, 0, stream>>>(x, W1, h);
    k_agg_post<<<N_NODES / 4, 256, 0, stream>>>(start, rows, wn, h, dinv, b1, gix, sums, cnt);
    k_final<<<N_GRAPHS, 256, 0, stream>>>(sums, cnt, fcW, fcb, out);
}

// Round 4
// 809.466 us; speedup vs baseline: 1.4311x; 1.0324x over previous
//
#include <hip/hip_runtime.h>
#include <stdint.h>

// Problem constants (match reference)
#define N_NODES  50000
#define N_EDGES  800000
#define D        256
#define D_OUT    16
#define N_GRAPHS 128

// JAX jax_threefry_partitionable=True: bits32(i) = fold(threefry2x32((0,42),(0,i))),
// fold = o0 ^ o1; keep iff top bit == 0.  (verified round 2, absmax 0.0)

__device__ __forceinline__ uint32_t rotl32(uint32_t x, int d) {
    return (x << d) | (x >> (32 - d));
}

__device__ __forceinline__ void threefry2x32(uint32_t k0, uint32_t k1,
                                             uint32_t c0, uint32_t c1,
                                             uint32_t& o0, uint32_t& o1) {
    uint32_t ks2 = k0 ^ k1 ^ 0x1BD11BDAu;
    uint32_t x0 = c0 + k0, x1 = c1 + k1;
    x0 += x1; x1 = rotl32(x1, 13); x1 ^= x0;
    x0 += x1; x1 = rotl32(x1, 15); x1 ^= x0;
    x0 += x1; x1 = rotl32(x1, 26); x1 ^= x0;
    x0 += x1; x1 = rotl32(x1, 6);  x1 ^= x0;
    x0 += k1; x1 += ks2 + 1u;
    x0 += x1; x1 = rotl32(x1, 17); x1 ^= x0;
    x0 += x1; x1 = rotl32(x1, 29); x1 ^= x0;
    x0 += x1; x1 = rotl32(x1, 16); x1 ^= x0;
    x0 += x1; x1 = rotl32(x1, 24); x1 ^= x0;
    x0 += ks2; x1 += k0 + 2u;
    x0 += x1; x1 = rotl32(x1, 13); x1 ^= x0;
    x0 += x1; x1 = rotl32(x1, 15); x1 ^= x0;
    x0 += x1; x1 = rotl32(x1, 26); x1 ^= x0;
    x0 += x1; x1 = rotl32(x1, 6);  x1 ^= x0;
    x0 += k0; x1 += k1 + 3u;
    x0 += x1; x1 = rotl32(x1, 17); x1 ^= x0;
    x0 += x1; x1 = rotl32(x1, 29); x1 ^= x0;
    x0 += x1; x1 = rotl32(x1, 16); x1 ^= x0;
    x0 += x1; x1 = rotl32(x1, 24); x1 ^= x0;
    x0 += k1; x1 += ks2 + 4u;
    x0 += x1; x1 = rotl32(x1, 13); x1 ^= x0;
    x0 += x1; x1 = rotl32(x1, 15); x1 ^= x0;
    x0 += x1; x1 = rotl32(x1, 26); x1 ^= x0;
    x0 += x1; x1 = rotl32(x1, 6);  x1 ^= x0;
    x0 += ks2; x1 += k0 + 5u;
    o0 = x0; o1 = x1;
}

__device__ __forceinline__ bool dropout_keep(uint32_t i) {
    uint32_t o0, o1;
    threefry2x32(0u, 42u, 0u, i, o0, o1);
    return ((o0 ^ o1) & 0x80000000u) == 0u;
}

__global__ __launch_bounds__(256) void k_deg_init(float* deg) {
    int i = blockIdx.x * 256 + threadIdx.x;
    if (i < N_NODES) deg[i] = 1.0f;   // self-loop weight
}

// fused: weighted degree (float atomics) + target histogram (int atomics)
__global__ __launch_bounds__(256) void k_deg_hist(const int* __restrict__ ei,
                                                  const float* __restrict__ ew,
                                                  float* __restrict__ deg,
                                                  int* __restrict__ start) {
    int e = blockIdx.x * 256 + threadIdx.x;
    if (e < N_EDGES) {
        int c = ei[N_EDGES + e];
        atomicAdd(&deg[c], ew[e]);
        atomicAdd(&start[c], 1);
    }
}

__global__ __launch_bounds__(256) void k_dinv(float* deg) {
    int i = blockIdx.x * 256 + threadIdx.x;
    if (i < N_NODES) {
        float d = deg[i];
        deg[i] = (d > 0.0f) ? rsqrtf(d) : 0.0f;
    }
}

// single-block exclusive scan of 50000 counts, in place; also copies to cursor
__global__ __launch_bounds__(1024) void k_scan(int* __restrict__ start,
                                               int* __restrict__ cursor) {
    __shared__ int part[1024];
    const int CH = 49;                     // 1024*49 = 50176 >= 50000
    int t = threadIdx.x;
    int lo = t * CH;
    int hi = lo + CH; if (hi > N_NODES) hi = N_NODES;
    int s = 0;
    for (int i = lo; i < hi; i++) s += start[i];
    part[t] = s;
    __syncthreads();
    for (int d = 1; d < 1024; d <<= 1) {
        int v = (t >= d) ? part[t - d] : 0;
        __syncthreads();
        part[t] += v;
        __syncthreads();
    }
    int run = part[t] - s;                 // exclusive base for this chunk
    for (int i = lo; i < hi; i++) {
        int c = start[i];
        start[i] = run;
        cursor[i] = run;
        run += c;
    }
    if (t == 1023) start[N_NODES] = run;
}

// scatter each edge's (row, norm) into its CSR slot
__global__ __launch_bounds__(256) void k_fill(const int* __restrict__ ei,
                                              const float* __restrict__ ew,
                                              const float* __restrict__ dinv,
                                              int* __restrict__ cursor,
                                              int* __restrict__ rows,
                                              float* __restrict__ wn) {
    int e = blockIdx.x * 256 + threadIdx.x;
    if (e < N_EDGES) {
        int r = ei[e];
        int c = ei[N_EDGES + e];
        int pos = atomicAdd(&cursor[c], 1);
        rows[pos] = r;
        wn[pos] = dinv[r] * ew[e] * dinv[c];
    }
}

// h = x @ W1  (16 nodes/block; thread t computes column t for all 16)
__global__ __launch_bounds__(256) void k_gemm(const float* __restrict__ x,
                                              const float* __restrict__ W,
                                              float* __restrict__ h) {
    __shared__ float4 xs[16][64];
    int t = threadIdx.x;
    int node0 = blockIdx.x * 16;
    const float4* xv = (const float4*)x;
    for (int i = t; i < 16 * 64; i += 256) {
        int m = i >> 6, c = i & 63;
        xs[m][c] = xv[(size_t)(node0 + m) * 64 + c];
    }
    __syncthreads();
    float acc[16];
#pragma unroll
    for (int m = 0; m < 16; m++) acc[m] = 0.0f;
    for (int kc = 0; kc < 64; kc++) {
        float w0 = W[(kc * 4 + 0) * D + t];
        float w1 = W[(kc * 4 + 1) * D + t];
        float w2 = W[(kc * 4 + 2) * D + t];
        float w3 = W[(kc * 4 + 3) * D + t];
#pragma unroll
        for (int m = 0; m < 16; m++) {
            float4 xm = xs[m][kc];
            acc[m] = fmaf(xm.x, w0, acc[m]);
            acc[m] = fmaf(xm.y, w1, acc[m]);
            acc[m] = fmaf(xm.z, w2, acc[m]);
            acc[m] = fmaf(xm.w, w3, acc[m]);
        }
    }
#pragma unroll
    for (int m = 0; m < 16; m++)
        h[(size_t)(node0 + m) * D + t] = acc[m];
}

// CSR aggregate + self-loop + bias + ReLU + dropout + pool atomics.
// One 64-lane wave per node (4 nodes/block), float4 per lane.
// Edge loop unrolled x4 with independent accumulators -> 4 gathers in flight.
__global__ __launch_bounds__(256) void k_agg_post(const int* __restrict__ start,
                                                  const int* __restrict__ rows,
                                                  const float* __restrict__ wn,
                                                  const float* __restrict__ h,
                                                  const float* __restrict__ dinv,
                                                  const float* __restrict__ b1,
                                                  const int* __restrict__ gidx,
                                                  float* __restrict__ sums,
                                                  float* __restrict__ cnt) {
    int n = blockIdx.x * 4 + (threadIdx.x >> 6);
    int l = threadIdx.x & 63;
    const float4* h4 = (const float4*)h;
    int s = start[n], e = start[n + 1];
    float4 a0 = make_float4(0.f, 0.f, 0.f, 0.f);
    float4 a1 = a0, a2 = a0, a3 = a0;
    int j = s;
    for (; j + 4 <= e; j += 4) {
        int   r0 = rows[j],   r1 = rows[j + 1], r2 = rows[j + 2], r3 = rows[j + 3];
        float w0 = wn[j],     w1 = wn[j + 1],   w2 = wn[j + 2],   w3 = wn[j + 3];
        float4 h0 = h4[(size_t)r0 * 64 + l];
        float4 h1 = h4[(size_t)r1 * 64 + l];
        float4 h2 = h4[(size_t)r2 * 64 + l];
        float4 h3 = h4[(size_t)r3 * 64 + l];
        a0.x = fmaf(w0, h0.x, a0.x); a0.y = fmaf(w0, h0.y, a0.y);
        a0.z = fmaf(w0, h0.z, a0.z); a0.w = fmaf(w0, h0.w, a0.w);
        a1.x = fmaf(w1, h1.x, a1.x); a1.y = fmaf(w1, h1.y, a1.y);
        a1.z = fmaf(w1, h1.z, a1.z); a1.w = fmaf(w1, h1.w, a1.w);
        a2.x = fmaf(w2, h2.x, a2.x); a2.y = fmaf(w2, h2.y, a2.y);
        a2.z = fmaf(w2, h2.z, a2.z); a2.w = fmaf(w2, h2.w, a2.w);
        a3.x = fmaf(w3, h3.x, a3.x); a3.y = fmaf(w3, h3.y, a3.y);
        a3.z = fmaf(w3, h3.z, a3.z); a3.w = fmaf(w3, h3.w, a3.w);
    }
    for (; j < e; j++) {
        int r = rows[j];
        float w = wn[j];
        float4 hv = h4[(size_t)r * 64 + l];
        a0.x = fmaf(w, hv.x, a0.x); a0.y = fmaf(w, hv.y, a0.y);
        a0.z = fmaf(w, hv.z, a0.z); a0.w = fmaf(w, hv.w, a0.w);
    }
    float4 acc;
    acc.x = (a0.x + a1.x) + (a2.x + a3.x);
    acc.y = (a0.y + a1.y) + (a2.y + a3.y);
    acc.z = (a0.z + a1.z) + (a2.z + a3.z);
    acc.w = (a0.w + a1.w) + (a2.w + a3.w);
    float di = dinv[n];
    float sl = di * di;
    float4 hn = h4[(size_t)n * 64 + l];
    float4 bv = ((const float4*)b1)[l];
    float v0 = fmaxf(fmaf(sl, hn.x, acc.x) + bv.x, 0.f);
    float v1 = fmaxf(fmaf(sl, hn.y, acc.y) + bv.y, 0.f);
    float v2 = fmaxf(fmaf(sl, hn.z, acc.z) + bv.z, 0.f);
    float v3 = fmaxf(fmaf(sl, hn.w, acc.w) + bv.w, 0.f);
    uint32_t base = (uint32_t)n * D + (uint32_t)l * 4u;
    v0 = dropout_keep(base + 0u) ? v0 * 2.f : 0.f;
    v1 = dropout_keep(base + 1u) ? v1 * 2.f : 0.f;
    v2 = dropout_keep(base + 2u) ? v2 * 2.f : 0.f;
    v3 = dropout_keep(base + 3u) ? v3 * 2.f : 0.f;
    int g = gidx[n];
    float* sg = &sums[(size_t)g * D + (size_t)l * 4];
    atomicAdd(sg + 0, v0);
    atomicAdd(sg + 1, v1);
    atomicAdd(sg + 2, v2);
    atomicAdd(sg + 3, v3);
    if (l == 0) atomicAdd(&cnt[g], 1.0f);
}

// pooled = sums/max(cnt,1);  out = pooled @ fc_W + fc_b
__global__ __launch_bounds__(256) void k_final(const float* __restrict__ sums,
                                               const float* __restrict__ cnt,
                                               const float* __restrict__ fcW,
                                               const float* __restrict__ fcb,
                                               float* __restrict__ out) {
    __shared__ float p[D];
    int g = blockIdx.x, t = threadIdx.x;
    float c = fmaxf(cnt[g], 1.0f);
    p[t] = sums[g * D + t] / c;
    __syncthreads();
    if (t < D_OUT) {
        float acc = fcb[t];
        for (int k = 0; k < D; k++)
            acc = fmaf(p[k], fcW[k * D_OUT + t], acc);
        out[g * D_OUT + t] = acc;
    }
}

extern "C" void kernel_launch(void* const* d_in, const int* in_sizes, int n_in,
                              void* d_out, int out_size, void* d_ws, size_t ws_size,
                              hipStream_t stream) {
    const float* x   = (const float*)d_in[0];
    const int*   ei  = (const int*)d_in[1];
    const float* ew  = (const float*)d_in[2];
    const int*   gix = (const int*)d_in[3];
    const float* W1  = (const float*)d_in[4];
    const float* b1  = (const float*)d_in[5];
    const float* fcW = (const float*)d_in[6];
    const float* fcb = (const float*)d_in[7];
    float* out = (float*)d_out;

    float* ws     = (float*)d_ws;
    float* dinv   = ws;
    float* h      = ws + 65536;
    int*   rows   = (int*)(h + (size_t)N_NODES * D);
    float* wn     = (float*)(rows + N_EDGES);
    int*   start  = (int*)(wn + N_EDGES);
    int*   cursor = start + 65536;
    float* sums   = (float*)(cursor + 65536);
    float* cnt    = sums + N_GRAPHS * D;

    // per-call re-init (replays don't re-poison)
    hipMemsetAsync(start, 0, (N_NODES + 1) * sizeof(int), stream);
    hipMemsetAsync(sums, 0, (N_GRAPHS * D + N_GRAPHS) * sizeof(float), stream);

    k_deg_init<<<(N_NODES + 255) / 256, 256, 0, stream>>>(dinv);
    k_deg_hist<<<(N_EDGES + 255) / 256, 256, 0, stream>>>(ei, ew, dinv, start);
    k_dinv<<<(N_NODES + 255) / 256, 256, 0, stream>>>(dinv);
    k_scan<<<1, 1024, 0, stream>>>(start, cursor);
    k_fill<<<(N_EDGES + 255) / 256, 256, 0, stream>>>(ei, ew, dinv, cursor, rows, wn);
    k_gemm<<<N_NODES / 16, 256, 0, stream>>>(x, W1, h);
    k_agg_post<<<N_NODES / 4, 256, 0, stream>>>(start, rows, wn, h, dinv, b1, gix, sums, cnt);
    k_final<<<N_GRAPHS, 256, 0, stream>>>(sums, cnt, fcW, fcb, out);
}

// Round 5
// 536.273 us; speedup vs baseline: 2.1601x; 1.5094x over previous
//
#include <hip/hip_runtime.h>
#include <stdint.h>

// Problem constants (match reference)
#define N_NODES  50000
#define N_EDGES  800000
#define D        256
#define D_OUT    16
#define N_GRAPHS 128

// JAX jax_threefry_partitionable=True: bits32(i) = fold(threefry2x32((0,42),(0,i))),
// fold = o0 ^ o1; keep iff top bit == 0.  (verified round 2, absmax 0.0)

__device__ __forceinline__ uint32_t rotl32(uint32_t x, int d) {
    return (x << d) | (x >> (32 - d));
}

__device__ __forceinline__ void threefry2x32(uint32_t k0, uint32_t k1,
                                             uint32_t c0, uint32_t c1,
                                             uint32_t& o0, uint32_t& o1) {
    uint32_t ks2 = k0 ^ k1 ^ 0x1BD11BDAu;
    uint32_t x0 = c0 + k0, x1 = c1 + k1;
    x0 += x1; x1 = rotl32(x1, 13); x1 ^= x0;
    x0 += x1; x1 = rotl32(x1, 15); x1 ^= x0;
    x0 += x1; x1 = rotl32(x1, 26); x1 ^= x0;
    x0 += x1; x1 = rotl32(x1, 6);  x1 ^= x0;
    x0 += k1; x1 += ks2 + 1u;
    x0 += x1; x1 = rotl32(x1, 17); x1 ^= x0;
    x0 += x1; x1 = rotl32(x1, 29); x1 ^= x0;
    x0 += x1; x1 = rotl32(x1, 16); x1 ^= x0;
    x0 += x1; x1 = rotl32(x1, 24); x1 ^= x0;
    x0 += ks2; x1 += k0 + 2u;
    x0 += x1; x1 = rotl32(x1, 13); x1 ^= x0;
    x0 += x1; x1 = rotl32(x1, 15); x1 ^= x0;
    x0 += x1; x1 = rotl32(x1, 26); x1 ^= x0;
    x0 += x1; x1 = rotl32(x1, 6);  x1 ^= x0;
    x0 += k0; x1 += k1 + 3u;
    x0 += x1; x1 = rotl32(x1, 17); x1 ^= x0;
    x0 += x1; x1 = rotl32(x1, 29); x1 ^= x0;
    x0 += x1; x1 = rotl32(x1, 16); x1 ^= x0;
    x0 += x1; x1 = rotl32(x1, 24); x1 ^= x0;
    x0 += k1; x1 += ks2 + 4u;
    x0 += x1; x1 = rotl32(x1, 13); x1 ^= x0;
    x0 += x1; x1 = rotl32(x1, 15); x1 ^= x0;
    x0 += x1; x1 = rotl32(x1, 26); x1 ^= x0;
    x0 += x1; x1 = rotl32(x1, 6);  x1 ^= x0;
    x0 += ks2; x1 += k0 + 5u;
    o0 = x0; o1 = x1;
}

__device__ __forceinline__ bool dropout_keep(uint32_t i) {
    uint32_t o0, o1;
    threefry2x32(0u, 42u, 0u, i, o0, o1);
    return ((o0 ^ o1) & 0x80000000u) == 0u;
}

__global__ __launch_bounds__(256) void k_deg_init(float* deg) {
    int i = blockIdx.x * 256 + threadIdx.x;
    if (i < N_NODES) deg[i] = 1.0f;   // self-loop weight
}

// fused: weighted degree (float atomics) + target histogram (int atomics)
// (these atomics hit 50000 RANDOM addresses -> no hot-line contention)
__global__ __launch_bounds__(256) void k_deg_hist(const int* __restrict__ ei,
                                                  const float* __restrict__ ew,
                                                  float* __restrict__ deg,
                                                  int* __restrict__ start) {
    int e = blockIdx.x * 256 + threadIdx.x;
    if (e < N_EDGES) {
        int c = ei[N_EDGES + e];
        atomicAdd(&deg[c], ew[e]);
        atomicAdd(&start[c], 1);
    }
}

__global__ __launch_bounds__(256) void k_dinv(float* deg) {
    int i = blockIdx.x * 256 + threadIdx.x;
    if (i < N_NODES) {
        float d = deg[i];
        deg[i] = (d > 0.0f) ? rsqrtf(d) : 0.0f;
    }
}

// single-block exclusive scan of 50000 counts, in place; also copies to cursor
__global__ __launch_bounds__(1024) void k_scan(int* __restrict__ start,
                                               int* __restrict__ cursor) {
    __shared__ int part[1024];
    const int CH = 49;                     // 1024*49 = 50176 >= 50000
    int t = threadIdx.x;
    int lo = t * CH;
    int hi = lo + CH; if (hi > N_NODES) hi = N_NODES;
    int s = 0;
    for (int i = lo; i < hi; i++) s += start[i];
    part[t] = s;
    __syncthreads();
    for (int d = 1; d < 1024; d <<= 1) {
        int v = (t >= d) ? part[t - d] : 0;
        __syncthreads();
        part[t] += v;
        __syncthreads();
    }
    int run = part[t] - s;                 // exclusive base for this chunk
    for (int i = lo; i < hi; i++) {
        int c = start[i];
        start[i] = run;
        cursor[i] = run;
        run += c;
    }
    if (t == 1023) start[N_NODES] = run;
}

// scatter each edge's (row, norm) into its CSR slot
__global__ __launch_bounds__(256) void k_fill(const int* __restrict__ ei,
                                              const float* __restrict__ ew,
                                              const float* __restrict__ dinv,
                                              int* __restrict__ cursor,
                                              int* __restrict__ rows,
                                              float* __restrict__ wn) {
    int e = blockIdx.x * 256 + threadIdx.x;
    if (e < N_EDGES) {
        int r = ei[e];
        int c = ei[N_EDGES + e];
        int pos = atomicAdd(&cursor[c], 1);
        rows[pos] = r;
        wn[pos] = dinv[r] * ew[e] * dinv[c];
    }
}

// h = x @ W1  (16 nodes/block; thread t computes column t for all 16)
__global__ __launch_bounds__(256) void k_gemm(const float* __restrict__ x,
                                              const float* __restrict__ W,
                                              float* __restrict__ h) {
    __shared__ float4 xs[16][64];
    int t = threadIdx.x;
    int node0 = blockIdx.x * 16;
    const float4* xv = (const float4*)x;
    for (int i = t; i < 16 * 64; i += 256) {
        int m = i >> 6, c = i & 63;
        xs[m][c] = xv[(size_t)(node0 + m) * 64 + c];
    }
    __syncthreads();
    float acc[16];
#pragma unroll
    for (int m = 0; m < 16; m++) acc[m] = 0.0f;
    for (int kc = 0; kc < 64; kc++) {
        float w0 = W[(kc * 4 + 0) * D + t];
        float w1 = W[(kc * 4 + 1) * D + t];
        float w2 = W[(kc * 4 + 2) * D + t];
        float w3 = W[(kc * 4 + 3) * D + t];
#pragma unroll
        for (int m = 0; m < 16; m++) {
            float4 xm = xs[m][kc];
            acc[m] = fmaf(xm.x, w0, acc[m]);
            acc[m] = fmaf(xm.y, w1, acc[m]);
            acc[m] = fmaf(xm.z, w2, acc[m]);
            acc[m] = fmaf(xm.w, w3, acc[m]);
        }
    }
#pragma unroll
    for (int m = 0; m < 16; m++)
        h[(size_t)(node0 + m) * D + t] = acc[m];
}

// CSR aggregate + self-loop + bias + ReLU + dropout -> y   (NO atomics)
// One 64-lane wave per node (4 nodes/block), float4 per lane, x8 unroll.
__global__ __launch_bounds__(256) void k_agg(const int* __restrict__ start,
                                             const int* __restrict__ rows,
                                             const float* __restrict__ wn,
                                             const float* __restrict__ h,
                                             const float* __restrict__ dinv,
                                             const float* __restrict__ b1,
                                             float* __restrict__ y) {
    int n = blockIdx.x * 4 + (threadIdx.x >> 6);
    int l = threadIdx.x & 63;
    const float4* h4 = (const float4*)h;
    int s = start[n], e = start[n + 1];
    float4 a0 = make_float4(0.f, 0.f, 0.f, 0.f);
    float4 a1 = a0, a2 = a0, a3 = a0, a4 = a0, a5 = a0, a6 = a0, a7 = a0;
    int j = s;
    for (; j + 8 <= e; j += 8) {
        int   r0 = rows[j],   r1 = rows[j+1], r2 = rows[j+2], r3 = rows[j+3];
        int   r4 = rows[j+4], r5 = rows[j+5], r6 = rows[j+6], r7 = rows[j+7];
        float w0 = wn[j],   w1 = wn[j+1], w2 = wn[j+2], w3 = wn[j+3];
        float w4 = wn[j+4], w5 = wn[j+5], w6 = wn[j+6], w7 = wn[j+7];
        float4 h0 = h4[(size_t)r0 * 64 + l];
        float4 h1 = h4[(size_t)r1 * 64 + l];
        float4 h2 = h4[(size_t)r2 * 64 + l];
        float4 h3 = h4[(size_t)r3 * 64 + l];
        float4 h5v = h4[(size_t)r5 * 64 + l];
        float4 h44 = h4[(size_t)r4 * 64 + l];
        float4 h6 = h4[(size_t)r6 * 64 + l];
        float4 h7 = h4[(size_t)r7 * 64 + l];
        a0.x = fmaf(w0, h0.x, a0.x); a0.y = fmaf(w0, h0.y, a0.y);
        a0.z = fmaf(w0, h0.z, a0.z); a0.w = fmaf(w0, h0.w, a0.w);
        a1.x = fmaf(w1, h1.x, a1.x); a1.y = fmaf(w1, h1.y, a1.y);
        a1.z = fmaf(w1, h1.z, a1.z); a1.w = fmaf(w1, h1.w, a1.w);
        a2.x = fmaf(w2, h2.x, a2.x); a2.y = fmaf(w2, h2.y, a2.y);
        a2.z = fmaf(w2, h2.z, a2.z); a2.w = fmaf(w2, h2.w, a2.w);
        a3.x = fmaf(w3, h3.x, a3.x); a3.y = fmaf(w3, h3.y, a3.y);
        a3.z = fmaf(w3, h3.z, a3.z); a3.w = fmaf(w3, h3.w, a3.w);
        a4.x = fmaf(w4, h44.x, a4.x); a4.y = fmaf(w4, h44.y, a4.y);
        a4.z = fmaf(w4, h44.z, a4.z); a4.w = fmaf(w4, h44.w, a4.w);
        a5.x = fmaf(w5, h5v.x, a5.x); a5.y = fmaf(w5, h5v.y, a5.y);
        a5.z = fmaf(w5, h5v.z, a5.z); a5.w = fmaf(w5, h5v.w, a5.w);
        a6.x = fmaf(w6, h6.x, a6.x); a6.y = fmaf(w6, h6.y, a6.y);
        a6.z = fmaf(w6, h6.z, a6.z); a6.w = fmaf(w6, h6.w, a6.w);
        a7.x = fmaf(w7, h7.x, a7.x); a7.y = fmaf(w7, h7.y, a7.y);
        a7.z = fmaf(w7, h7.z, a7.z); a7.w = fmaf(w7, h7.w, a7.w);
    }
    for (; j < e; j++) {
        int r = rows[j];
        float w = wn[j];
        float4 hv = h4[(size_t)r * 64 + l];
        a0.x = fmaf(w, hv.x, a0.x); a0.y = fmaf(w, hv.y, a0.y);
        a0.z = fmaf(w, hv.z, a0.z); a0.w = fmaf(w, hv.w, a0.w);
    }
    float4 acc;
    acc.x = ((a0.x + a1.x) + (a2.x + a3.x)) + ((a4.x + a5.x) + (a6.x + a7.x));
    acc.y = ((a0.y + a1.y) + (a2.y + a3.y)) + ((a4.y + a5.y) + (a6.y + a7.y));
    acc.z = ((a0.z + a1.z) + (a2.z + a3.z)) + ((a4.z + a5.z) + (a6.z + a7.z));
    acc.w = ((a0.w + a1.w) + (a2.w + a3.w)) + ((a4.w + a5.w) + (a6.w + a7.w));
    float di = dinv[n];
    float sl = di * di;
    float4 hn = h4[(size_t)n * 64 + l];
    float4 bv = ((const float4*)b1)[l];
    float v0 = fmaxf(fmaf(sl, hn.x, acc.x) + bv.x, 0.f);
    float v1 = fmaxf(fmaf(sl, hn.y, acc.y) + bv.y, 0.f);
    float v2 = fmaxf(fmaf(sl, hn.z, acc.z) + bv.z, 0.f);
    float v3 = fmaxf(fmaf(sl, hn.w, acc.w) + bv.w, 0.f);
    uint32_t base = (uint32_t)n * D + (uint32_t)l * 4u;
    v0 = dropout_keep(base + 0u) ? v0 * 2.f : 0.f;
    v1 = dropout_keep(base + 1u) ? v1 * 2.f : 0.f;
    v2 = dropout_keep(base + 2u) ? v2 * 2.f : 0.f;
    v3 = dropout_keep(base + 3u) ? v3 * 2.f : 0.f;
    ((float4*)y)[(size_t)n * 64 + l] = make_float4(v0, v1, v2, v3);
}

// Segmented mean over sorted graph ids: one block per graph, column-parallel.
// Atomic-free: binary search the contiguous [lo,hi) node range of graph g.
__global__ __launch_bounds__(256) void k_pool(const float* __restrict__ y,
                                              const int* __restrict__ gidx,
                                              float* __restrict__ pooled) {
    __shared__ int sh[2];
    int g = blockIdx.x, t = threadIdx.x;
    if (t == 0) {
        // lower_bound(g) and lower_bound(g+1) on sorted gidx
        int lo = 0, hi = N_NODES;
        while (lo < hi) { int m = (lo + hi) >> 1; if (gidx[m] < g) lo = m + 1; else hi = m; }
        sh[0] = lo;
        int lo2 = lo; hi = N_NODES;
        while (lo2 < hi) { int m = (lo2 + hi) >> 1; if (gidx[m] < g + 1) lo2 = m + 1; else hi = m; }
        sh[1] = lo2;
    }
    __syncthreads();
    int lo = sh[0], hi = sh[1];
    float s0 = 0.f, s1 = 0.f, s2 = 0.f, s3 = 0.f;
    float s4 = 0.f, s5 = 0.f, s6 = 0.f, s7 = 0.f;
    int r = lo;
    for (; r + 8 <= hi; r += 8) {
        s0 += y[(size_t)(r + 0) * D + t];
        s1 += y[(size_t)(r + 1) * D + t];
        s2 += y[(size_t)(r + 2) * D + t];
        s3 += y[(size_t)(r + 3) * D + t];
        s4 += y[(size_t)(r + 4) * D + t];
        s5 += y[(size_t)(r + 5) * D + t];
        s6 += y[(size_t)(r + 6) * D + t];
        s7 += y[(size_t)(r + 7) * D + t];
    }
    for (; r < hi; r++) s0 += y[(size_t)r * D + t];
    float s = ((s0 + s1) + (s2 + s3)) + ((s4 + s5) + (s6 + s7));
    float c = (float)(hi - lo);
    pooled[(size_t)g * D + t] = s / fmaxf(c, 1.0f);
}

// out = pooled @ fc_W + fc_b
__global__ __launch_bounds__(256) void k_final(const float* __restrict__ pooled,
                                               const float* __restrict__ fcW,
                                               const float* __restrict__ fcb,
                                               float* __restrict__ out) {
    __shared__ float p[D];
    int g = blockIdx.x, t = threadIdx.x;
    p[t] = pooled[(size_t)g * D + t];
    __syncthreads();
    if (t < D_OUT) {
        float acc = fcb[t];
        for (int k = 0; k < D; k++)
            acc = fmaf(p[k], fcW[k * D_OUT + t], acc);
        out[g * D_OUT + t] = acc;
    }
}

extern "C" void kernel_launch(void* const* d_in, const int* in_sizes, int n_in,
                              void* d_out, int out_size, void* d_ws, size_t ws_size,
                              hipStream_t stream) {
    const float* x   = (const float*)d_in[0];
    const int*   ei  = (const int*)d_in[1];
    const float* ew  = (const float*)d_in[2];
    const int*   gix = (const int*)d_in[3];
    const float* W1  = (const float*)d_in[4];
    const float* b1  = (const float*)d_in[5];
    const float* fcW = (const float*)d_in[6];
    const float* fcb = (const float*)d_in[7];
    float* out = (float*)d_out;

    float* ws     = (float*)d_ws;
    float* dinv   = ws;                                   //    65,536
    float* h      = ws + 65536;                           // 12,800,000
    int*   rows   = (int*)(h + (size_t)N_NODES * D);      //    800,000
    float* wn     = (float*)(rows + N_EDGES);             //    800,000
    int*   start  = (int*)(wn + N_EDGES);                 //     65,536
    int*   cursor = start + 65536;                        //     65,536
    float* y      = (float*)(cursor + 65536);             // 12,800,000
    float* pooled = y + (size_t)N_NODES * D;              //     32,768
    // total ~27.4M floats = ~110 MB

    // per-call re-init (replays don't re-poison)
    hipMemsetAsync(start, 0, (N_NODES + 1) * sizeof(int), stream);

    k_deg_init<<<(N_NODES + 255) / 256, 256, 0, stream>>>(dinv);
    k_deg_hist<<<(N_EDGES + 255) / 256, 256, 0, stream>>>(ei, ew, dinv, start);
    k_dinv<<<(N_NODES + 255) / 256, 256, 0, stream>>>(dinv);
    k_scan<<<1, 1024, 0, stream>>>(start, cursor);
    k_fill<<<(N_EDGES + 255) / 256, 256, 0, stream>>>(ei, ew, dinv, cursor, rows, wn);
    k_gemm<<<N_NODES / 16, 256, 0, stream>>>(x, W1, h);
    k_agg<<<N_NODES / 4, 256, 0, stream>>>(start, rows, wn, h, dinv, b1, y);
    k_pool<<<N_GRAPHS, 256, 0, stream>>>(y, gix, pooled);
    k_final<<<N_GRAPHS, 256, 0, stream>>>(pooled, fcW, fcb, out);
}

// Round 6
// 466.982 us; speedup vs baseline: 2.4806x; 1.1484x over previous
//
#include <hip/hip_runtime.h>
#include <stdint.h>

// Problem constants (match reference)
#define N_NODES  50000
#define N_EDGES  800000
#define D        256
#define D_OUT    16
#define N_GRAPHS 128

// JAX jax_threefry_partitionable=True: bits32(i) = fold(threefry2x32((0,42),(0,i))),
// fold = o0 ^ o1; keep iff top bit == 0.  (verified round 2, absmax 0.0)

__device__ __forceinline__ uint32_t rotl32(uint32_t x, int d) {
    return (x << d) | (x >> (32 - d));
}

__device__ __forceinline__ void threefry2x32(uint32_t k0, uint32_t k1,
                                             uint32_t c0, uint32_t c1,
                                             uint32_t& o0, uint32_t& o1) {
    uint32_t ks2 = k0 ^ k1 ^ 0x1BD11BDAu;
    uint32_t x0 = c0 + k0, x1 = c1 + k1;
    x0 += x1; x1 = rotl32(x1, 13); x1 ^= x0;
    x0 += x1; x1 = rotl32(x1, 15); x1 ^= x0;
    x0 += x1; x1 = rotl32(x1, 26); x1 ^= x0;
    x0 += x1; x1 = rotl32(x1, 6);  x1 ^= x0;
    x0 += k1; x1 += ks2 + 1u;
    x0 += x1; x1 = rotl32(x1, 17); x1 ^= x0;
    x0 += x1; x1 = rotl32(x1, 29); x1 ^= x0;
    x0 += x1; x1 = rotl32(x1, 16); x1 ^= x0;
    x0 += x1; x1 = rotl32(x1, 24); x1 ^= x0;
    x0 += ks2; x1 += k0 + 2u;
    x0 += x1; x1 = rotl32(x1, 13); x1 ^= x0;
    x0 += x1; x1 = rotl32(x1, 15); x1 ^= x0;
    x0 += x1; x1 = rotl32(x1, 26); x1 ^= x0;
    x0 += x1; x1 = rotl32(x1, 6);  x1 ^= x0;
    x0 += k0; x1 += k1 + 3u;
    x0 += x1; x1 = rotl32(x1, 17); x1 ^= x0;
    x0 += x1; x1 = rotl32(x1, 29); x1 ^= x0;
    x0 += x1; x1 = rotl32(x1, 16); x1 ^= x0;
    x0 += x1; x1 = rotl32(x1, 24); x1 ^= x0;
    x0 += k1; x1 += ks2 + 4u;
    x0 += x1; x1 = rotl32(x1, 13); x1 ^= x0;
    x0 += x1; x1 = rotl32(x1, 15); x1 ^= x0;
    x0 += x1; x1 = rotl32(x1, 26); x1 ^= x0;
    x0 += x1; x1 = rotl32(x1, 6);  x1 ^= x0;
    x0 += ks2; x1 += k0 + 5u;
    o0 = x0; o1 = x1;
}

__device__ __forceinline__ bool dropout_keep(uint32_t i) {
    uint32_t o0, o1;
    threefry2x32(0u, 42u, 0u, i, o0, o1);
    return ((o0 ^ o1) & 0x80000000u) == 0u;
}

__device__ __forceinline__ uint32_t bf16_rne(float f) {   // fp32 -> bf16 bits (RNE)
    uint32_t u = __float_as_uint(f);
    return (u + 0x7FFFu + ((u >> 16) & 1u)) >> 16;
}
__device__ __forceinline__ float bf2f(unsigned short u) {
    return __uint_as_float((uint32_t)u << 16);
}

// deg = 1 (self-loop), start = 0   (replaces memset + k_deg_init)
__global__ __launch_bounds__(256) void k_init(float* deg, int* start) {
    int i = blockIdx.x * 256 + threadIdx.x;
    if (i < N_NODES) deg[i] = 1.0f;
    if (i < N_NODES + 1) start[i] = 0;
}

// fused: weighted degree (float atomics) + target histogram (int atomics)
__global__ __launch_bounds__(256) void k_deg_hist(const int* __restrict__ ei,
                                                  const float* __restrict__ ew,
                                                  float* __restrict__ deg,
                                                  int* __restrict__ start) {
    int e = blockIdx.x * 256 + threadIdx.x;
    if (e < N_EDGES) {
        int c = ei[N_EDGES + e];
        atomicAdd(&deg[c], ew[e]);
        atomicAdd(&start[c], 1);
    }
}

// single block: deg->dinv (in place) + exclusive scan of start, copy to cursor
__global__ __launch_bounds__(1024) void k_scan(float* __restrict__ deg,
                                               int* __restrict__ start,
                                               int* __restrict__ cursor) {
    int t = threadIdx.x;
    for (int i = t; i < N_NODES; i += 1024) {
        float d = deg[i];
        deg[i] = (d > 0.0f) ? rsqrtf(d) : 0.0f;
    }
    __shared__ int part[1024];
    const int CH = 49;                     // 1024*49 = 50176 >= 50000
    int lo = t * CH;
    int hi = lo + CH; if (hi > N_NODES) hi = N_NODES;
    int s = 0;
    for (int i = lo; i < hi; i++) s += start[i];
    part[t] = s;
    __syncthreads();
    for (int d = 1; d < 1024; d <<= 1) {
        int v = (t >= d) ? part[t - d] : 0;
        __syncthreads();
        part[t] += v;
        __syncthreads();
    }
    int run = part[t] - s;                 // exclusive base for this chunk
    for (int i = lo; i < hi; i++) {
        int c = start[i];
        start[i] = run;
        cursor[i] = run;
        run += c;
    }
    if (t == 1023) start[N_NODES] = run;
}

// scatter each edge's (row, norm) into its CSR slot
__global__ __launch_bounds__(256) void k_fill(const int* __restrict__ ei,
                                              const float* __restrict__ ew,
                                              const float* __restrict__ dinv,
                                              int* __restrict__ cursor,
                                              int* __restrict__ rows,
                                              float* __restrict__ wn) {
    int e = blockIdx.x * 256 + threadIdx.x;
    if (e < N_EDGES) {
        int r = ei[e];
        int c = ei[N_EDGES + e];
        int pos = atomicAdd(&cursor[c], 1);
        rows[pos] = r;
        wn[pos] = dinv[r] * ew[e] * dinv[c];
    }
}

// h = x @ W1, stored as packed bf16 (RNE).
// 32 nodes/block, 256 threads: thread = (node-half g, col-pair c2).
// Each thread: 16 nodes x 2 cols = 32 fp32 accumulators.
// xs reads are wave-uniform (broadcast, conflict-free); 16 LDS reads feed 128 FMAs.
__global__ __launch_bounds__(256) void k_gemm(const float* __restrict__ x,
                                              const float* __restrict__ W,
                                              uint32_t* __restrict__ hb2) {
    __shared__ float4 xs[32][64];          // 32 KB
    int tid = threadIdx.x;
    int node0 = blockIdx.x * 32;
    const float4* xv = (const float4*)x;
    for (int i = tid; i < 32 * 64; i += 256) {
        int m = i >> 6, c = i & 63;
        int nn = node0 + m; if (nn >= N_NODES) nn = N_NODES - 1;   // tail clamp
        xs[m][c] = xv[(size_t)nn * 64 + c];
    }
    __syncthreads();
    int c2 = tid & 127;        // col pair: cols 2*c2, 2*c2+1
    int g  = tid >> 7;         // node half: nodes node0+16g .. +15
    float acc0[16], acc1[16];
#pragma unroll
    for (int m = 0; m < 16; m++) { acc0[m] = 0.f; acc1[m] = 0.f; }
    const float2* W2 = (const float2*)W;   // [256][128] float2
    for (int kc = 0; kc < 64; kc++) {
        float2 wa = W2[(size_t)(4 * kc + 0) * 128 + c2];
        float2 wb = W2[(size_t)(4 * kc + 1) * 128 + c2];
        float2 wc = W2[(size_t)(4 * kc + 2) * 128 + c2];
        float2 wd = W2[(size_t)(4 * kc + 3) * 128 + c2];
#pragma unroll
        for (int m = 0; m < 16; m++) {
            float4 xm = xs[g * 16 + m][kc];
            acc0[m] = fmaf(xm.x, wa.x, acc0[m]);
            acc1[m] = fmaf(xm.x, wa.y, acc1[m]);
            acc0[m] = fmaf(xm.y, wb.x, acc0[m]);
            acc1[m] = fmaf(xm.y, wb.y, acc1[m]);
            acc0[m] = fmaf(xm.z, wc.x, acc0[m]);
            acc1[m] = fmaf(xm.z, wc.y, acc1[m]);
            acc0[m] = fmaf(xm.w, wd.x, acc0[m]);
            acc1[m] = fmaf(xm.w, wd.y, acc1[m]);
        }
    }
#pragma unroll
    for (int m = 0; m < 16; m++) {
        int n = node0 + g * 16 + m;
        if (n < N_NODES)
            hb2[(size_t)n * 128 + c2] = bf16_rne(acc0[m]) | (bf16_rne(acc1[m]) << 16);
    }
}

// CSR aggregate (bf16 h gathers) + self-loop + bias + ReLU + dropout -> y (f32)
// One 64-lane wave per node (4 nodes/block); lane l covers cols 4l..4l+3 (8B loads).
__global__ __launch_bounds__(256) void k_agg(const int* __restrict__ start,
                                             const int* __restrict__ rows,
                                             const float* __restrict__ wn,
                                             const ushort* __restrict__ hb,
                                             const float* __restrict__ dinv,
                                             const float* __restrict__ b1,
                                             float* __restrict__ y) {
    int n = blockIdx.x * 4 + (threadIdx.x >> 6);
    int l = threadIdx.x & 63;
    const ushort4* h4 = (const ushort4*)hb;   // 64 ushort4 per row
    int s = start[n], e = start[n + 1];
    float4 a0 = make_float4(0.f, 0.f, 0.f, 0.f);
    float4 a1 = a0, a2 = a0, a3 = a0, a4 = a0, a5 = a0, a6 = a0, a7 = a0;
    int j = s;
    for (; j + 8 <= e; j += 8) {
        int   r0 = rows[j],   r1 = rows[j+1], r2 = rows[j+2], r3 = rows[j+3];
        int   r4 = rows[j+4], r5 = rows[j+5], r6 = rows[j+6], r7 = rows[j+7];
        float w0 = wn[j],   w1 = wn[j+1], w2 = wn[j+2], w3 = wn[j+3];
        float w4 = wn[j+4], w5 = wn[j+5], w6 = wn[j+6], w7 = wn[j+7];
        ushort4 u0 = h4[(size_t)r0 * 64 + l];
        ushort4 u1 = h4[(size_t)r1 * 64 + l];
        ushort4 u2 = h4[(size_t)r2 * 64 + l];
        ushort4 u3 = h4[(size_t)r3 * 64 + l];
        ushort4 u4 = h4[(size_t)r4 * 64 + l];
        ushort4 u5 = h4[(size_t)r5 * 64 + l];
        ushort4 u6 = h4[(size_t)r6 * 64 + l];
        ushort4 u7 = h4[(size_t)r7 * 64 + l];
        a0.x = fmaf(w0, bf2f(u0.x), a0.x); a0.y = fmaf(w0, bf2f(u0.y), a0.y);
        a0.z = fmaf(w0, bf2f(u0.z), a0.z); a0.w = fmaf(w0, bf2f(u0.w), a0.w);
        a1.x = fmaf(w1, bf2f(u1.x), a1.x); a1.y = fmaf(w1, bf2f(u1.y), a1.y);
        a1.z = fmaf(w1, bf2f(u1.z), a1.z); a1.w = fmaf(w1, bf2f(u1.w), a1.w);
        a2.x = fmaf(w2, bf2f(u2.x), a2.x); a2.y = fmaf(w2, bf2f(u2.y), a2.y);
        a2.z = fmaf(w2, bf2f(u2.z), a2.z); a2.w = fmaf(w2, bf2f(u2.w), a2.w);
        a3.x = fmaf(w3, bf2f(u3.x), a3.x); a3.y = fmaf(w3, bf2f(u3.y), a3.y);
        a3.z = fmaf(w3, bf2f(u3.z), a3.z); a3.w = fmaf(w3, bf2f(u3.w), a3.w);
        a4.x = fmaf(w4, bf2f(u4.x), a4.x); a4.y = fmaf(w4, bf2f(u4.y), a4.y);
        a4.z = fmaf(w4, bf2f(u4.z), a4.z); a4.w = fmaf(w4, bf2f(u4.w), a4.w);
        a5.x = fmaf(w5, bf2f(u5.x), a5.x); a5.y = fmaf(w5, bf2f(u5.y), a5.y);
        a5.z = fmaf(w5, bf2f(u5.z), a5.z); a5.w = fmaf(w5, bf2f(u5.w), a5.w);
        a6.x = fmaf(w6, bf2f(u6.x), a6.x); a6.y = fmaf(w6, bf2f(u6.y), a6.y);
        a6.z = fmaf(w6, bf2f(u6.z), a6.z); a6.w = fmaf(w6, bf2f(u6.w), a6.w);
        a7.x = fmaf(w7, bf2f(u7.x), a7.x); a7.y = fmaf(w7, bf2f(u7.y), a7.y);
        a7.z = fmaf(w7, bf2f(u7.z), a7.z); a7.w = fmaf(w7, bf2f(u7.w), a7.w);
    }
    for (; j < e; j++) {
        int r = rows[j];
        float w = wn[j];
        ushort4 uv = h4[(size_t)r * 64 + l];
        a0.x = fmaf(w, bf2f(uv.x), a0.x); a0.y = fmaf(w, bf2f(uv.y), a0.y);
        a0.z = fmaf(w, bf2f(uv.z), a0.z); a0.w = fmaf(w, bf2f(uv.w), a0.w);
    }
    float4 acc;
    acc.x = ((a0.x + a1.x) + (a2.x + a3.x)) + ((a4.x + a5.x) + (a6.x + a7.x));
    acc.y = ((a0.y + a1.y) + (a2.y + a3.y)) + ((a4.y + a5.y) + (a6.y + a7.y));
    acc.z = ((a0.z + a1.z) + (a2.z + a3.z)) + ((a4.z + a5.z) + (a6.z + a7.z));
    acc.w = ((a0.w + a1.w) + (a2.w + a3.w)) + ((a4.w + a5.w) + (a6.w + a7.w));
    float di = dinv[n];
    float sl = di * di;
    ushort4 un = h4[(size_t)n * 64 + l];
    float4 bv = ((const float4*)b1)[l];
    float v0 = fmaxf(fmaf(sl, bf2f(un.x), acc.x) + bv.x, 0.f);
    float v1 = fmaxf(fmaf(sl, bf2f(un.y), acc.y) + bv.y, 0.f);
    float v2 = fmaxf(fmaf(sl, bf2f(un.z), acc.z) + bv.z, 0.f);
    float v3 = fmaxf(fmaf(sl, bf2f(un.w), acc.w) + bv.w, 0.f);
    uint32_t base = (uint32_t)n * D + (uint32_t)l * 4u;
    v0 = dropout_keep(base + 0u) ? v0 * 2.f : 0.f;
    v1 = dropout_keep(base + 1u) ? v1 * 2.f : 0.f;
    v2 = dropout_keep(base + 2u) ? v2 * 2.f : 0.f;
    v3 = dropout_keep(base + 3u) ? v3 * 2.f : 0.f;
    ((float4*)y)[(size_t)n * 64 + l] = make_float4(v0, v1, v2, v3);
}

// Fused segmented-mean pool + FC: one block per graph (index is sorted).
__global__ __launch_bounds__(256) void k_poolfinal(const float* __restrict__ y,
                                                   const int* __restrict__ gidx,
                                                   const float* __restrict__ fcW,
                                                   const float* __restrict__ fcb,
                                                   float* __restrict__ out) {
    __shared__ int sh[2];
    __shared__ float p[D];
    int g = blockIdx.x, t = threadIdx.x;
    if (t == 0) {
        int lo = 0, hi = N_NODES;
        while (lo < hi) { int m = (lo + hi) >> 1; if (gidx[m] < g) lo = m + 1; else hi = m; }
        sh[0] = lo;
        int lo2 = lo; hi = N_NODES;
        while (lo2 < hi) { int m = (lo2 + hi) >> 1; if (gidx[m] < g + 1) lo2 = m + 1; else hi = m; }
        sh[1] = lo2;
    }
    __syncthreads();
    int lo = sh[0], hi = sh[1];
    float s0 = 0.f, s1 = 0.f, s2 = 0.f, s3 = 0.f;
    float s4 = 0.f, s5 = 0.f, s6 = 0.f, s7 = 0.f;
    int r = lo;
    for (; r + 8 <= hi; r += 8) {
        s0 += y[(size_t)(r + 0) * D + t];
        s1 += y[(size_t)(r + 1) * D + t];
        s2 += y[(size_t)(r + 2) * D + t];
        s3 += y[(size_t)(r + 3) * D + t];
        s4 += y[(size_t)(r + 4) * D + t];
        s5 += y[(size_t)(r + 5) * D + t];
        s6 += y[(size_t)(r + 6) * D + t];
        s7 += y[(size_t)(r + 7) * D + t];
    }
    for (; r < hi; r++) s0 += y[(size_t)r * D + t];
    float s = ((s0 + s1) + (s2 + s3)) + ((s4 + s5) + (s6 + s7));
    float c = (float)(hi - lo);
    p[t] = s / fmaxf(c, 1.0f);
    __syncthreads();
    if (t < D_OUT) {
        float acc = fcb[t];
        for (int k = 0; k < D; k++)
            acc = fmaf(p[k], fcW[k * D_OUT + t], acc);
        out[g * D_OUT + t] = acc;
    }
}

extern "C" void kernel_launch(void* const* d_in, const int* in_sizes, int n_in,
                              void* d_out, int out_size, void* d_ws, size_t ws_size,
                              hipStream_t stream) {
    const float* x   = (const float*)d_in[0];
    const int*   ei  = (const int*)d_in[1];
    const float* ew  = (const float*)d_in[2];
    const int*   gix = (const int*)d_in[3];
    const float* W1  = (const float*)d_in[4];
    const float* b1  = (const float*)d_in[5];
    const float* fcW = (const float*)d_in[6];
    const float* fcb = (const float*)d_in[7];
    float* out = (float*)d_out;

    float*  ws     = (float*)d_ws;
    float*  dinv   = ws;                                  //     65,536 f
    ushort* hb     = (ushort*)(ws + 65536);               // 12.8M bf16 = 6.4M f
    int*    rows   = (int*)(ws + 65536 + 6400000);        //    800,000
    float*  wn     = (float*)(rows + N_EDGES);            //    800,000
    int*    start  = (int*)(wn + N_EDGES);                //     65,536
    int*    cursor = start + 65536;                       //     65,536
    float*  y      = (float*)(cursor + 65536);            // 12,800,000
    // total ~21.0M floats = ~84 MB

    k_init<<<(N_NODES + 256) / 256, 256, 0, stream>>>(dinv, start);
    k_deg_hist<<<(N_EDGES + 255) / 256, 256, 0, stream>>>(ei, ew, dinv, start);
    k_scan<<<1, 1024, 0, stream>>>(dinv, start, cursor);
    k_fill<<<(N_EDGES + 255) / 256, 256, 0, stream>>>(ei, ew, dinv, cursor, rows, wn);
    k_gemm<<<(N_NODES + 31) / 32, 256, 0, stream>>>(x, W1, (uint32_t*)hb);
    k_agg<<<N_NODES / 4, 256, 0, stream>>>(start, rows, wn, hb, dinv, b1, y);
    k_poolfinal<<<N_GRAPHS, 256, 0, stream>>>(y, gix, fcW, fcb, out);
}

// Round 7
// 351.657 us; speedup vs baseline: 3.2941x; 1.3279x over previous
//
#include <hip/hip_runtime.h>
#include <stdint.h>

// Problem constants (match reference)
#define N_NODES  50000
#define N_EDGES  800000
#define D        256
#define D_OUT    16
#define N_GRAPHS 128
#define NB_SCAN  196        // 196*256 = 50176 >= N_NODES+1

// JAX jax_threefry_partitionable=True: bits32(i) = fold(threefry2x32((0,42),(0,i))),
// fold = o0 ^ o1; keep iff top bit == 0.  (verified round 2, absmax 0.0)

__device__ __forceinline__ uint32_t rotl32(uint32_t x, int d) {
    return (x << d) | (x >> (32 - d));
}

__device__ __forceinline__ void threefry2x32(uint32_t k0, uint32_t k1,
                                             uint32_t c0, uint32_t c1,
                                             uint32_t& o0, uint32_t& o1) {
    uint32_t ks2 = k0 ^ k1 ^ 0x1BD11BDAu;
    uint32_t x0 = c0 + k0, x1 = c1 + k1;
    x0 += x1; x1 = rotl32(x1, 13); x1 ^= x0;
    x0 += x1; x1 = rotl32(x1, 15); x1 ^= x0;
    x0 += x1; x1 = rotl32(x1, 26); x1 ^= x0;
    x0 += x1; x1 = rotl32(x1, 6);  x1 ^= x0;
    x0 += k1; x1 += ks2 + 1u;
    x0 += x1; x1 = rotl32(x1, 17); x1 ^= x0;
    x0 += x1; x1 = rotl32(x1, 29); x1 ^= x0;
    x0 += x1; x1 = rotl32(x1, 16); x1 ^= x0;
    x0 += x1; x1 = rotl32(x1, 24); x1 ^= x0;
    x0 += ks2; x1 += k0 + 2u;
    x0 += x1; x1 = rotl32(x1, 13); x1 ^= x0;
    x0 += x1; x1 = rotl32(x1, 15); x1 ^= x0;
    x0 += x1; x1 = rotl32(x1, 26); x1 ^= x0;
    x0 += x1; x1 = rotl32(x1, 6);  x1 ^= x0;
    x0 += k0; x1 += k1 + 3u;
    x0 += x1; x1 = rotl32(x1, 17); x1 ^= x0;
    x0 += x1; x1 = rotl32(x1, 29); x1 ^= x0;
    x0 += x1; x1 = rotl32(x1, 16); x1 ^= x0;
    x0 += x1; x1 = rotl32(x1, 24); x1 ^= x0;
    x0 += k1; x1 += ks2 + 4u;
    x0 += x1; x1 = rotl32(x1, 13); x1 ^= x0;
    x0 += x1; x1 = rotl32(x1, 15); x1 ^= x0;
    x0 += x1; x1 = rotl32(x1, 26); x1 ^= x0;
    x0 += x1; x1 = rotl32(x1, 6);  x1 ^= x0;
    x0 += ks2; x1 += k0 + 5u;
    o0 = x0; o1 = x1;
}

__device__ __forceinline__ bool dropout_keep(uint32_t i) {
    uint32_t o0, o1;
    threefry2x32(0u, 42u, 0u, i, o0, o1);
    return ((o0 ^ o1) & 0x80000000u) == 0u;
}

__device__ __forceinline__ uint32_t bf16_rne(float f) {   // fp32 -> bf16 bits (RNE)
    uint32_t u = __float_as_uint(f);
    return (u + 0x7FFFu + ((u >> 16) & 1u)) >> 16;
}
__device__ __forceinline__ float bf2f(unsigned short u) {
    return __uint_as_float((uint32_t)u << 16);
}

// deg = 1 (self-loop), start = 0
__global__ __launch_bounds__(256) void k_init(float* deg, int* start) {
    int i = blockIdx.x * 256 + threadIdx.x;
    if (i < N_NODES) deg[i] = 1.0f;
    if (i < N_NODES + 1) start[i] = 0;
}

// fused: weighted degree (float atomics) + target histogram (int atomics)
__global__ __launch_bounds__(256) void k_deg_hist(const int* __restrict__ ei,
                                                  const float* __restrict__ ew,
                                                  float* __restrict__ deg,
                                                  int* __restrict__ start) {
    int e = blockIdx.x * 256 + threadIdx.x;
    if (e < N_EDGES) {
        int c = ei[N_EDGES + e];
        atomicAdd(&deg[c], ew[e]);
        atomicAdd(&start[c], 1);
    }
}

// scan phase 1: coalesced dinv conversion + per-block reduce of start counts
__global__ __launch_bounds__(256) void k_scan1(float* __restrict__ deg,
                                               const int* __restrict__ start,
                                               int* __restrict__ partial) {
    __shared__ int sd[256];
    int t = threadIdx.x;
    int i = blockIdx.x * 256 + t;
    if (i < N_NODES) {
        float d = deg[i];
        deg[i] = (d > 0.0f) ? rsqrtf(d) : 0.0f;
    }
    int v = (i < N_NODES) ? start[i] : 0;
    sd[t] = v;
    __syncthreads();
    for (int d = 128; d > 0; d >>= 1) {
        if (t < d) sd[t] += sd[t + d];
        __syncthreads();
    }
    if (t == 0) partial[blockIdx.x] = sd[0];
}

// scan phase 2: single block exclusive-scans the NB_SCAN partials
__global__ __launch_bounds__(256) void k_scan2(int* __restrict__ partial,
                                               int* __restrict__ partialExc) {
    __shared__ int sd[256];
    int t = threadIdx.x;
    int v = (t < NB_SCAN) ? partial[t] : 0;
    sd[t] = v;
    __syncthreads();
    for (int d = 1; d < 256; d <<= 1) {
        int u = (t >= d) ? sd[t - d] : 0;
        __syncthreads();
        sd[t] += u;
        __syncthreads();
    }
    if (t < NB_SCAN) partialExc[t] = sd[t] - v;   // exclusive
    if (t == 255) partialExc[NB_SCAN] = sd[255];  // grand total
}

// scan phase 3: per-block LDS scan + base offset -> start/cursor (coalesced)
__global__ __launch_bounds__(256) void k_scan3(int* __restrict__ start,
                                               int* __restrict__ cursor,
                                               const int* __restrict__ partialExc) {
    __shared__ int sd[256];
    int t = threadIdx.x;
    int i = blockIdx.x * 256 + t;
    int v = (i < N_NODES) ? start[i] : 0;
    sd[t] = v;
    __syncthreads();
    for (int d = 1; d < 256; d <<= 1) {
        int u = (t >= d) ? sd[t - d] : 0;
        __syncthreads();
        sd[t] += u;
        __syncthreads();
    }
    int val = partialExc[blockIdx.x] + sd[t] - v;  // exclusive prefix
    if (i < N_NODES) {
        start[i] = val;
        cursor[i] = val;
    } else if (i == N_NODES) {
        start[N_NODES] = partialExc[NB_SCAN];
    }
}

// scatter each edge's (row, norm) into its CSR slot
__global__ __launch_bounds__(256) void k_fill(const int* __restrict__ ei,
                                              const float* __restrict__ ew,
                                              const float* __restrict__ dinv,
                                              int* __restrict__ cursor,
                                              int* __restrict__ rows,
                                              float* __restrict__ wn) {
    int e = blockIdx.x * 256 + threadIdx.x;
    if (e < N_EDGES) {
        int r = ei[e];
        int c = ei[N_EDGES + e];
        int pos = atomicAdd(&cursor[c], 1);
        rows[pos] = r;
        wn[pos] = dinv[r] * ew[e] * dinv[c];
    }
}

// h = x @ W1, stored as packed bf16 (RNE).
// 32 nodes/block, 256 threads: thread = (node-half g, col-pair c2).
__global__ __launch_bounds__(256) void k_gemm(const float* __restrict__ x,
                                              const float* __restrict__ W,
                                              uint32_t* __restrict__ hb2) {
    __shared__ float4 xs[32][64];          // 32 KB
    int tid = threadIdx.x;
    int node0 = blockIdx.x * 32;
    const float4* xv = (const float4*)x;
    for (int i = tid; i < 32 * 64; i += 256) {
        int m = i >> 6, c = i & 63;
        int nn = node0 + m; if (nn >= N_NODES) nn = N_NODES - 1;   // tail clamp
        xs[m][c] = xv[(size_t)nn * 64 + c];
    }
    __syncthreads();
    int c2 = tid & 127;        // col pair: cols 2*c2, 2*c2+1
    int g  = tid >> 7;         // node half
    float acc0[16], acc1[16];
#pragma unroll
    for (int m = 0; m < 16; m++) { acc0[m] = 0.f; acc1[m] = 0.f; }
    const float2* W2 = (const float2*)W;   // [256][128] float2
    for (int kc = 0; kc < 64; kc++) {
        float2 wa = W2[(size_t)(4 * kc + 0) * 128 + c2];
        float2 wb = W2[(size_t)(4 * kc + 1) * 128 + c2];
        float2 wc = W2[(size_t)(4 * kc + 2) * 128 + c2];
        float2 wd = W2[(size_t)(4 * kc + 3) * 128 + c2];
#pragma unroll
        for (int m = 0; m < 16; m++) {
            float4 xm = xs[g * 16 + m][kc];
            acc0[m] = fmaf(xm.x, wa.x, acc0[m]);
            acc1[m] = fmaf(xm.x, wa.y, acc1[m]);
            acc0[m] = fmaf(xm.y, wb.x, acc0[m]);
            acc1[m] = fmaf(xm.y, wb.y, acc1[m]);
            acc0[m] = fmaf(xm.z, wc.x, acc0[m]);
            acc1[m] = fmaf(xm.z, wc.y, acc1[m]);
            acc0[m] = fmaf(xm.w, wd.x, acc0[m]);
            acc1[m] = fmaf(xm.w, wd.y, acc1[m]);
        }
    }
#pragma unroll
    for (int m = 0; m < 16; m++) {
        int n = node0 + g * 16 + m;
        if (n < N_NODES)
            hb2[(size_t)n * 128 + c2] = bf16_rne(acc0[m]) | (bf16_rne(acc1[m]) << 16);
    }
}

// CSR aggregate (bf16 h gathers) + self-loop + bias + ReLU + dropout -> y (f32)
__global__ __launch_bounds__(256) void k_agg(const int* __restrict__ start,
                                             const int* __restrict__ rows,
                                             const float* __restrict__ wn,
                                             const ushort* __restrict__ hb,
                                             const float* __restrict__ dinv,
                                             const float* __restrict__ b1,
                                             float* __restrict__ y) {
    int n = blockIdx.x * 4 + (threadIdx.x >> 6);
    int l = threadIdx.x & 63;
    const ushort4* h4 = (const ushort4*)hb;   // 64 ushort4 per row
    int s = start[n], e = start[n + 1];
    float4 a0 = make_float4(0.f, 0.f, 0.f, 0.f);
    float4 a1 = a0, a2 = a0, a3 = a0, a4 = a0, a5 = a0, a6 = a0, a7 = a0;
    int j = s;
    for (; j + 8 <= e; j += 8) {
        int   r0 = rows[j],   r1 = rows[j+1], r2 = rows[j+2], r3 = rows[j+3];
        int   r4 = rows[j+4], r5 = rows[j+5], r6 = rows[j+6], r7 = rows[j+7];
        float w0 = wn[j],   w1 = wn[j+1], w2 = wn[j+2], w3 = wn[j+3];
        float w4 = wn[j+4], w5 = wn[j+5], w6 = wn[j+6], w7 = wn[j+7];
        ushort4 u0 = h4[(size_t)r0 * 64 + l];
        ushort4 u1 = h4[(size_t)r1 * 64 + l];
        ushort4 u2 = h4[(size_t)r2 * 64 + l];
        ushort4 u3 = h4[(size_t)r3 * 64 + l];
        ushort4 u4 = h4[(size_t)r4 * 64 + l];
        ushort4 u5 = h4[(size_t)r5 * 64 + l];
        ushort4 u6 = h4[(size_t)r6 * 64 + l];
        ushort4 u7 = h4[(size_t)r7 * 64 + l];
        a0.x = fmaf(w0, bf2f(u0.x), a0.x); a0.y = fmaf(w0, bf2f(u0.y), a0.y);
        a0.z = fmaf(w0, bf2f(u0.z), a0.z); a0.w = fmaf(w0, bf2f(u0.w), a0.w);
        a1.x = fmaf(w1, bf2f(u1.x), a1.x); a1.y = fmaf(w1, bf2f(u1.y), a1.y);
        a1.z = fmaf(w1, bf2f(u1.z), a1.z); a1.w = fmaf(w1, bf2f(u1.w), a1.w);
        a2.x = fmaf(w2, bf2f(u2.x), a2.x); a2.y = fmaf(w2, bf2f(u2.y), a2.y);
        a2.z = fmaf(w2, bf2f(u2.z), a2.z); a2.w = fmaf(w2, bf2f(u2.w), a2.w);
        a3.x = fmaf(w3, bf2f(u3.x), a3.x); a3.y = fmaf(w3, bf2f(u3.y), a3.y);
        a3.z = fmaf(w3, bf2f(u3.z), a3.z); a3.w = fmaf(w3, bf2f(u3.w), a3.w);
        a4.x = fmaf(w4, bf2f(u4.x), a4.x); a4.y = fmaf(w4, bf2f(u4.y), a4.y);
        a4.z = fmaf(w4, bf2f(u4.z), a4.z); a4.w = fmaf(w4, bf2f(u4.w), a4.w);
        a5.x = fmaf(w5, bf2f(u5.x), a5.x); a5.y = fmaf(w5, bf2f(u5.y), a5.y);
        a5.z = fmaf(w5, bf2f(u5.z), a5.z); a5.w = fmaf(w5, bf2f(u5.w), a5.w);
        a6.x = fmaf(w6, bf2f(u6.x), a6.x); a6.y = fmaf(w6, bf2f(u6.y), a6.y);
        a6.z = fmaf(w6, bf2f(u6.z), a6.z); a6.w = fmaf(w6, bf2f(u6.w), a6.w);
        a7.x = fmaf(w7, bf2f(u7.x), a7.x); a7.y = fmaf(w7, bf2f(u7.y), a7.y);
        a7.z = fmaf(w7, bf2f(u7.z), a7.z); a7.w = fmaf(w7, bf2f(u7.w), a7.w);
    }
    for (; j < e; j++) {
        int r = rows[j];
        float w = wn[j];
        ushort4 uv = h4[(size_t)r * 64 + l];
        a0.x = fmaf(w, bf2f(uv.x), a0.x); a0.y = fmaf(w, bf2f(uv.y), a0.y);
        a0.z = fmaf(w, bf2f(uv.z), a0.z); a0.w = fmaf(w, bf2f(uv.w), a0.w);
    }
    float4 acc;
    acc.x = ((a0.x + a1.x) + (a2.x + a3.x)) + ((a4.x + a5.x) + (a6.x + a7.x));
    acc.y = ((a0.y + a1.y) + (a2.y + a3.y)) + ((a4.y + a5.y) + (a6.y + a7.y));
    acc.z = ((a0.z + a1.z) + (a2.z + a3.z)) + ((a4.z + a5.z) + (a6.z + a7.z));
    acc.w = ((a0.w + a1.w) + (a2.w + a3.w)) + ((a4.w + a5.w) + (a6.w + a7.w));
    float di = dinv[n];
    float sl = di * di;
    ushort4 un = h4[(size_t)n * 64 + l];
    float4 bv = ((const float4*)b1)[l];
    float v0 = fmaxf(fmaf(sl, bf2f(un.x), acc.x) + bv.x, 0.f);
    float v1 = fmaxf(fmaf(sl, bf2f(un.y), acc.y) + bv.y, 0.f);
    float v2 = fmaxf(fmaf(sl, bf2f(un.z), acc.z) + bv.z, 0.f);
    float v3 = fmaxf(fmaf(sl, bf2f(un.w), acc.w) + bv.w, 0.f);
    uint32_t base = (uint32_t)n * D + (uint32_t)l * 4u;
    v0 = dropout_keep(base + 0u) ? v0 * 2.f : 0.f;
    v1 = dropout_keep(base + 1u) ? v1 * 2.f : 0.f;
    v2 = dropout_keep(base + 2u) ? v2 * 2.f : 0.f;
    v3 = dropout_keep(base + 3u) ? v3 * 2.f : 0.f;
    ((float4*)y)[(size_t)n * 64 + l] = make_float4(v0, v1, v2, v3);
}

// Fused segmented-mean pool + FC: one block per graph (index is sorted).
__global__ __launch_bounds__(256) void k_poolfinal(const float* __restrict__ y,
                                                   const int* __restrict__ gidx,
                                                   const float* __restrict__ fcW,
                                                   const float* __restrict__ fcb,
                                                   float* __restrict__ out) {
    __shared__ int sh[2];
    __shared__ float p[D];
    int g = blockIdx.x, t = threadIdx.x;
    if (t == 0) {
        int lo = 0, hi = N_NODES;
        while (lo < hi) { int m = (lo + hi) >> 1; if (gidx[m] < g) lo = m + 1; else hi = m; }
        sh[0] = lo;
        int lo2 = lo; hi = N_NODES;
        while (lo2 < hi) { int m = (lo2 + hi) >> 1; if (gidx[m] < g + 1) lo2 = m + 1; else hi = m; }
        sh[1] = lo2;
    }
    __syncthreads();
    int lo = sh[0], hi = sh[1];
    float s0 = 0.f, s1 = 0.f, s2 = 0.f, s3 = 0.f;
    float s4 = 0.f, s5 = 0.f, s6 = 0.f, s7 = 0.f;
    int r = lo;
    for (; r + 8 <= hi; r += 8) {
        s0 += y[(size_t)(r + 0) * D + t];
        s1 += y[(size_t)(r + 1) * D + t];
        s2 += y[(size_t)(r + 2) * D + t];
        s3 += y[(size_t)(r + 3) * D + t];
        s4 += y[(size_t)(r + 4) * D + t];
        s5 += y[(size_t)(r + 5) * D + t];
        s6 += y[(size_t)(r + 6) * D + t];
        s7 += y[(size_t)(r + 7) * D + t];
    }
    for (; r < hi; r++) s0 += y[(size_t)r * D + t];
    float s = ((s0 + s1) + (s2 + s3)) + ((s4 + s5) + (s6 + s7));
    float c = (float)(hi - lo);
    p[t] = s / fmaxf(c, 1.0f);
    __syncthreads();
    if (t < D_OUT) {
        float acc = fcb[t];
        for (int k = 0; k < D; k++)
            acc = fmaf(p[k], fcW[k * D_OUT + t], acc);
        out[g * D_OUT + t] = acc;
    }
}

extern "C" void kernel_launch(void* const* d_in, const int* in_sizes, int n_in,
                              void* d_out, int out_size, void* d_ws, size_t ws_size,
                              hipStream_t stream) {
    const float* x   = (const float*)d_in[0];
    const int*   ei  = (const int*)d_in[1];
    const float* ew  = (const float*)d_in[2];
    const int*   gix = (const int*)d_in[3];
    const float* W1  = (const float*)d_in[4];
    const float* b1  = (const float*)d_in[5];
    const float* fcW = (const float*)d_in[6];
    const float* fcb = (const float*)d_in[7];
    float* out = (float*)d_out;

    float*  ws     = (float*)d_ws;
    float*  dinv   = ws;                                  //     65,536 f
    ushort* hb     = (ushort*)(ws + 65536);               // 12.8M bf16 = 6.4M f
    int*    rows   = (int*)(ws + 65536 + 6400000);        //    800,000
    float*  wn     = (float*)(rows + N_EDGES);            //    800,000
    int*    start  = (int*)(wn + N_EDGES);                //     65,536
    int*    cursor = start + 65536;                       //     65,536
    int*    partial    = cursor + 65536;                  //        256
    int*    partialExc = partial + 256;                   //        256
    float*  y      = (float*)(partialExc + 256);          // 12,800,000
    // total ~21.0M floats = ~84 MB

    k_init<<<(N_NODES + 256) / 256, 256, 0, stream>>>(dinv, start);
    k_deg_hist<<<(N_EDGES + 255) / 256, 256, 0, stream>>>(ei, ew, dinv, start);
    k_scan1<<<NB_SCAN, 256, 0, stream>>>(dinv, start, partial);
    k_scan2<<<1, 256, 0, stream>>>(partial, partialExc);
    k_scan3<<<NB_SCAN, 256, 0, stream>>>(start, cursor, partialExc);
    k_fill<<<(N_EDGES + 255) / 256, 256, 0, stream>>>(ei, ew, dinv, cursor, rows, wn);
    k_gemm<<<(N_NODES + 31) / 32, 256, 0, stream>>>(x, W1, (uint32_t*)hb);
    k_agg<<<N_NODES / 4, 256, 0, stream>>>(start, rows, wn, hb, dinv, b1, y);
    k_poolfinal<<<N_GRAPHS, 256, 0, stream>>>(y, gix, fcW, fcb, out);
}

// Round 8
// 293.218 us; speedup vs baseline: 3.9507x; 1.1993x over previous
//
#include <hip/hip_runtime.h>
#include <stdint.h>

// Problem constants (match reference)
#define N_NODES  50000
#define N_EDGES  800000
#define D        256
#define D_OUT    16
#define N_GRAPHS 128
#define NB_SCAN  196        // 196*256 = 50176 >= N_NODES+1

// JAX jax_threefry_partitionable=True: bits32(i) = fold(threefry2x32((0,42),(0,i))),
// fold = o0 ^ o1; keep iff top bit == 0.  (verified round 2, absmax 0.0)

typedef short bf16x8 __attribute__((ext_vector_type(8)));
typedef float f32x4  __attribute__((ext_vector_type(4)));

__device__ __forceinline__ uint32_t rotl32(uint32_t x, int d) {
    return (x << d) | (x >> (32 - d));
}

__device__ __forceinline__ void threefry2x32(uint32_t k0, uint32_t k1,
                                             uint32_t c0, uint32_t c1,
                                             uint32_t& o0, uint32_t& o1) {
    uint32_t ks2 = k0 ^ k1 ^ 0x1BD11BDAu;
    uint32_t x0 = c0 + k0, x1 = c1 + k1;
    x0 += x1; x1 = rotl32(x1, 13); x1 ^= x0;
    x0 += x1; x1 = rotl32(x1, 15); x1 ^= x0;
    x0 += x1; x1 = rotl32(x1, 26); x1 ^= x0;
    x0 += x1; x1 = rotl32(x1, 6);  x1 ^= x0;
    x0 += k1; x1 += ks2 + 1u;
    x0 += x1; x1 = rotl32(x1, 17); x1 ^= x0;
    x0 += x1; x1 = rotl32(x1, 29); x1 ^= x0;
    x0 += x1; x1 = rotl32(x1, 16); x1 ^= x0;
    x0 += x1; x1 = rotl32(x1, 24); x1 ^= x0;
    x0 += ks2; x1 += k0 + 2u;
    x0 += x1; x1 = rotl32(x1, 13); x1 ^= x0;
    x0 += x1; x1 = rotl32(x1, 15); x1 ^= x0;
    x0 += x1; x1 = rotl32(x1, 26); x1 ^= x0;
    x0 += x1; x1 = rotl32(x1, 6);  x1 ^= x0;
    x0 += k0; x1 += k1 + 3u;
    x0 += x1; x1 = rotl32(x1, 17); x1 ^= x0;
    x0 += x1; x1 = rotl32(x1, 29); x1 ^= x0;
    x0 += x1; x1 = rotl32(x1, 16); x1 ^= x0;
    x0 += x1; x1 = rotl32(x1, 24); x1 ^= x0;
    x0 += k1; x1 += ks2 + 4u;
    x0 += x1; x1 = rotl32(x1, 13); x1 ^= x0;
    x0 += x1; x1 = rotl32(x1, 15); x1 ^= x0;
    x0 += x1; x1 = rotl32(x1, 26); x1 ^= x0;
    x0 += x1; x1 = rotl32(x1, 6);  x1 ^= x0;
    x0 += ks2; x1 += k0 + 5u;
    o0 = x0; o1 = x1;
}

__device__ __forceinline__ bool dropout_keep(uint32_t i) {
    uint32_t o0, o1;
    threefry2x32(0u, 42u, 0u, i, o0, o1);
    return ((o0 ^ o1) & 0x80000000u) == 0u;
}

__device__ __forceinline__ uint32_t bf16_rne(float f) {   // fp32 -> bf16 bits (RNE)
    uint32_t u = __float_as_uint(f);
    return (u + 0x7FFFu + ((u >> 16) & 1u)) >> 16;
}
__device__ __forceinline__ float bf2f(unsigned short u) {
    return __uint_as_float((uint32_t)u << 16);
}

// deg = 1 (self-loop), start = 0
__global__ __launch_bounds__(256) void k_init(float* deg, int* start) {
    int i = blockIdx.x * 256 + threadIdx.x;
    if (i < N_NODES) deg[i] = 1.0f;
    if (i < N_NODES + 1) start[i] = 0;
}

// fused: weighted degree (float atomics) + target histogram (int atomics)
__global__ __launch_bounds__(256) void k_deg_hist(const int* __restrict__ ei,
                                                  const float* __restrict__ ew,
                                                  float* __restrict__ deg,
                                                  int* __restrict__ start) {
    int e = blockIdx.x * 256 + threadIdx.x;
    if (e < N_EDGES) {
        int c = ei[N_EDGES + e];
        atomicAdd(&deg[c], ew[e]);
        atomicAdd(&start[c], 1);
    }
}

// scan phase 1: coalesced dinv conversion + per-block reduce of start counts
__global__ __launch_bounds__(256) void k_scan1(float* __restrict__ deg,
                                               const int* __restrict__ start,
                                               int* __restrict__ partial) {
    __shared__ int sd[256];
    int t = threadIdx.x;
    int i = blockIdx.x * 256 + t;
    if (i < N_NODES) {
        float d = deg[i];
        deg[i] = (d > 0.0f) ? rsqrtf(d) : 0.0f;
    }
    int v = (i < N_NODES) ? start[i] : 0;
    sd[t] = v;
    __syncthreads();
    for (int d = 128; d > 0; d >>= 1) {
        if (t < d) sd[t] += sd[t + d];
        __syncthreads();
    }
    if (t == 0) partial[blockIdx.x] = sd[0];
}

// scan phase 2: single block exclusive-scans the NB_SCAN partials
__global__ __launch_bounds__(256) void k_scan2(int* __restrict__ partial,
                                               int* __restrict__ partialExc) {
    __shared__ int sd[256];
    int t = threadIdx.x;
    int v = (t < NB_SCAN) ? partial[t] : 0;
    sd[t] = v;
    __syncthreads();
    for (int d = 1; d < 256; d <<= 1) {
        int u = (t >= d) ? sd[t - d] : 0;
        __syncthreads();
        sd[t] += u;
        __syncthreads();
    }
    if (t < NB_SCAN) partialExc[t] = sd[t] - v;   // exclusive
    if (t == 255) partialExc[NB_SCAN] = sd[255];  // grand total
}

// scan phase 3: per-block LDS scan + base offset -> start/cursor (coalesced)
__global__ __launch_bounds__(256) void k_scan3(int* __restrict__ start,
                                               int* __restrict__ cursor,
                                               const int* __restrict__ partialExc) {
    __shared__ int sd[256];
    int t = threadIdx.x;
    int i = blockIdx.x * 256 + t;
    int v = (i < N_NODES) ? start[i] : 0;
    sd[t] = v;
    __syncthreads();
    for (int d = 1; d < 256; d <<= 1) {
        int u = (t >= d) ? sd[t - d] : 0;
        __syncthreads();
        sd[t] += u;
        __syncthreads();
    }
    int val = partialExc[blockIdx.x] + sd[t] - v;  // exclusive prefix
    if (i < N_NODES) {
        start[i] = val;
        cursor[i] = val;
    } else if (i == N_NODES) {
        start[N_NODES] = partialExc[NB_SCAN];
    }
}

// scatter each edge's (row, norm) into its CSR slot
__global__ __launch_bounds__(256) void k_fill(const int* __restrict__ ei,
                                              const float* __restrict__ ew,
                                              const float* __restrict__ dinv,
                                              int* __restrict__ cursor,
                                              int* __restrict__ rows,
                                              float* __restrict__ wn) {
    int e = blockIdx.x * 256 + threadIdx.x;
    if (e < N_EDGES) {
        int r = ei[e];
        int c = ei[N_EDGES + e];
        int pos = atomicAdd(&cursor[c], 1);
        rows[pos] = r;
        wn[pos] = dinv[r] * ew[e] * dinv[c];
    }
}

// ---------------- MFMA GEMM: h(bf16) = x(f32->bf16) @ W1(f32->bf16) --------
// Block: 64 (M=nodes) x 64 (N=cols), K=256 staged fully in LDS as bf16.
// A_lds[row][k] and Bt_lds[n][k], both [64][256] bf16 (32 KB each),
// XOR-swizzled (byte ^= (row&7)<<4) so b128 frag reads are ~conflict-free.
// 4 waves as 2x2; each wave 32x32 = 2x2 fragments of mfma_f32_16x16x32_bf16.
__device__ __forceinline__ int swz(int row, int kByte) {
    return (row << 9) + (kByte ^ ((row & 7) << 4));
}

__global__ __launch_bounds__(256) void k_gemm(const float* __restrict__ x,
                                              const float* __restrict__ W,
                                              ushort* __restrict__ hb) {
    __shared__ __align__(16) char smem[65536];   // A: [0,32K), Bt: [32K,64K)
    int tid = threadIdx.x;
    int Mbase = blockIdx.x * 64;
    int Nbase = blockIdx.y * 64;

    // ---- stage A: x[Mbase..+63][0..255] -> bf16, swizzled ----
    const float4* xv = (const float4*)x;
#pragma unroll
    for (int i = 0; i < 16; i++) {
        int f = tid + i * 256;        // flat float4 id, 0..4095
        int r = f >> 6;               // row 0..63
        int c4 = f & 63;              // float4 index -> k = 4*c4
        int node = Mbase + r; if (node >= N_NODES) node = N_NODES - 1;
        float4 v = xv[(size_t)node * 64 + c4];
        uint32_t p0 = bf16_rne(v.x) | (bf16_rne(v.y) << 16);
        uint32_t p1 = bf16_rne(v.z) | (bf16_rne(v.w) << 16);
        *(uint2*)(smem + swz(r, c4 * 8)) = make_uint2(p0, p1);
    }
    // ---- stage Bt: W[k][Nbase+n] -> Bt[n][k] bf16, swizzled ----
    {
        int n = tid & 63;             // col within tile
        int og = tid >> 6;            // octet group 0..3
#pragma unroll
        for (int i = 0; i < 8; i++) {
            int k0 = (og + 4 * i) * 8;
            uint32_t q0, q1, q2, q3;
            q0 = bf16_rne(W[(size_t)(k0 + 0) * 256 + Nbase + n]) |
                 (bf16_rne(W[(size_t)(k0 + 1) * 256 + Nbase + n]) << 16);
            q1 = bf16_rne(W[(size_t)(k0 + 2) * 256 + Nbase + n]) |
                 (bf16_rne(W[(size_t)(k0 + 3) * 256 + Nbase + n]) << 16);
            q2 = bf16_rne(W[(size_t)(k0 + 4) * 256 + Nbase + n]) |
                 (bf16_rne(W[(size_t)(k0 + 5) * 256 + Nbase + n]) << 16);
            q3 = bf16_rne(W[(size_t)(k0 + 6) * 256 + Nbase + n]) |
                 (bf16_rne(W[(size_t)(k0 + 7) * 256 + Nbase + n]) << 16);
            *(uint4*)(smem + 32768 + swz(n, k0 * 2)) = make_uint4(q0, q1, q2, q3);
        }
    }
    __syncthreads();

    // ---- MFMA main loop ----
    int l = tid & 63;
    int w = tid >> 6;
    int wr = w >> 1, wc = w & 1;          // wave grid 2x2, each 32x32
    int lr = l & 15;                      // frag row (A) / col (B)
    int kg = l >> 4;                      // k-group 0..3 (8 k each)
    f32x4 acc00 = {0.f, 0.f, 0.f, 0.f};
    f32x4 acc01 = acc00, acc10 = acc00, acc11 = acc00;
#pragma unroll
    for (int ks = 0; ks < 8; ks++) {
        int kB = ks * 64 + kg * 16;       // byte offset of this lane's 8 k
        bf16x8 a0 = *(const bf16x8*)(smem + swz(wr * 32 + lr, kB));
        bf16x8 a1 = *(const bf16x8*)(smem + swz(wr * 32 + 16 + lr, kB));
        bf16x8 b0 = *(const bf16x8*)(smem + 32768 + swz(wc * 32 + lr, kB));
        bf16x8 b1 = *(const bf16x8*)(smem + 32768 + swz(wc * 32 + 16 + lr, kB));
        acc00 = __builtin_amdgcn_mfma_f32_16x16x32_bf16(a0, b0, acc00, 0, 0, 0);
        acc01 = __builtin_amdgcn_mfma_f32_16x16x32_bf16(a0, b1, acc01, 0, 0, 0);
        acc10 = __builtin_amdgcn_mfma_f32_16x16x32_bf16(a1, b0, acc10, 0, 0, 0);
        acc11 = __builtin_amdgcn_mfma_f32_16x16x32_bf16(a1, b1, acc11, 0, 0, 0);
    }
    // ---- store: D layout row=(l>>4)*4+r, col=l&15  (m89-verified) ----
    int drow = (l >> 4) * 4;
    int dcol = l & 15;
#pragma unroll
    for (int r = 0; r < 4; r++) {
        int n0 = Mbase + wr * 32 + drow + r;
        int n1 = n0 + 16;
        int c0 = Nbase + wc * 32 + dcol;
        if (n0 < N_NODES) {
            hb[(size_t)n0 * 256 + c0]      = (ushort)bf16_rne(acc00[r]);
            hb[(size_t)n0 * 256 + c0 + 16] = (ushort)bf16_rne(acc01[r]);
        }
        if (n1 < N_NODES) {
            hb[(size_t)n1 * 256 + c0]      = (ushort)bf16_rne(acc10[r]);
            hb[(size_t)n1 * 256 + c0 + 16] = (ushort)bf16_rne(acc11[r]);
        }
    }
}

// CSR aggregate (bf16 h gathers) + self-loop + bias + ReLU + dropout -> y (f32)
__global__ __launch_bounds__(256) void k_agg(const int* __restrict__ start,
                                             const int* __restrict__ rows,
                                             const float* __restrict__ wn,
                                             const ushort* __restrict__ hb,
                                             const float* __restrict__ dinv,
                                             const float* __restrict__ b1,
                                             float* __restrict__ y) {
    int n = blockIdx.x * 4 + (threadIdx.x >> 6);
    int l = threadIdx.x & 63;
    const ushort4* h4 = (const ushort4*)hb;   // 64 ushort4 per row
    int s = start[n], e = start[n + 1];
    float4 a0 = make_float4(0.f, 0.f, 0.f, 0.f);
    float4 a1 = a0, a2 = a0, a3 = a0, a4 = a0, a5 = a0, a6 = a0, a7 = a0;
    int j = s;
    for (; j + 8 <= e; j += 8) {
        int   r0 = rows[j],   r1 = rows[j+1], r2 = rows[j+2], r3 = rows[j+3];
        int   r4 = rows[j+4], r5 = rows[j+5], r6 = rows[j+6], r7 = rows[j+7];
        float w0 = wn[j],   w1 = wn[j+1], w2 = wn[j+2], w3 = wn[j+3];
        float w4 = wn[j+4], w5 = wn[j+5], w6 = wn[j+6], w7 = wn[j+7];
        ushort4 u0 = h4[(size_t)r0 * 64 + l];
        ushort4 u1 = h4[(size_t)r1 * 64 + l];
        ushort4 u2 = h4[(size_t)r2 * 64 + l];
        ushort4 u3 = h4[(size_t)r3 * 64 + l];
        ushort4 u4 = h4[(size_t)r4 * 64 + l];
        ushort4 u5 = h4[(size_t)r5 * 64 + l];
        ushort4 u6 = h4[(size_t)r6 * 64 + l];
        ushort4 u7 = h4[(size_t)r7 * 64 + l];
        a0.x = fmaf(w0, bf2f(u0.x), a0.x); a0.y = fmaf(w0, bf2f(u0.y), a0.y);
        a0.z = fmaf(w0, bf2f(u0.z), a0.z); a0.w = fmaf(w0, bf2f(u0.w), a0.w);
        a1.x = fmaf(w1, bf2f(u1.x), a1.x); a1.y = fmaf(w1, bf2f(u1.y), a1.y);
        a1.z = fmaf(w1, bf2f(u1.z), a1.z); a1.w = fmaf(w1, bf2f(u1.w), a1.w);
        a2.x = fmaf(w2, bf2f(u2.x), a2.x); a2.y = fmaf(w2, bf2f(u2.y), a2.y);
        a2.z = fmaf(w2, bf2f(u2.z), a2.z); a2.w = fmaf(w2, bf2f(u2.w), a2.w);
        a3.x = fmaf(w3, bf2f(u3.x), a3.x); a3.y = fmaf(w3, bf2f(u3.y), a3.y);
        a3.z = fmaf(w3, bf2f(u3.z), a3.z); a3.w = fmaf(w3, bf2f(u3.w), a3.w);
        a4.x = fmaf(w4, bf2f(u4.x), a4.x); a4.y = fmaf(w4, bf2f(u4.y), a4.y);
        a4.z = fmaf(w4, bf2f(u4.z), a4.z); a4.w = fmaf(w4, bf2f(u4.w), a4.w);
        a5.x = fmaf(w5, bf2f(u5.x), a5.x); a5.y = fmaf(w5, bf2f(u5.y), a5.y);
        a5.z = fmaf(w5, bf2f(u5.z), a5.z); a5.w = fmaf(w5, bf2f(u5.w), a5.w);
        a6.x = fmaf(w6, bf2f(u6.x), a6.x); a6.y = fmaf(w6, bf2f(u6.y), a6.y);
        a6.z = fmaf(w6, bf2f(u6.z), a6.z); a6.w = fmaf(w6, bf2f(u6.w), a6.w);
        a7.x = fmaf(w7, bf2f(u7.x), a7.x); a7.y = fmaf(w7, bf2f(u7.y), a7.y);
        a7.z = fmaf(w7, bf2f(u7.z), a7.z); a7.w = fmaf(w7, bf2f(u7.w), a7.w);
    }
    for (; j < e; j++) {
        int r = rows[j];
        float w = wn[j];
        ushort4 uv = h4[(size_t)r * 64 + l];
        a0.x = fmaf(w, bf2f(uv.x), a0.x); a0.y = fmaf(w, bf2f(uv.y), a0.y);
        a0.z = fmaf(w, bf2f(uv.z), a0.z); a0.w = fmaf(w, bf2f(uv.w), a0.w);
    }
    float4 acc;
    acc.x = ((a0.x + a1.x) + (a2.x + a3.x)) + ((a4.x + a5.x) + (a6.x + a7.x));
    acc.y = ((a0.y + a1.y) + (a2.y + a3.y)) + ((a4.y + a5.y) + (a6.y + a7.y));
    acc.z = ((a0.z + a1.z) + (a2.z + a3.z)) + ((a4.z + a5.z) + (a6.z + a7.z));
    acc.w = ((a0.w + a1.w) + (a2.w + a3.w)) + ((a4.w + a5.w) + (a6.w + a7.w));
    float di = dinv[n];
    float sl = di * di;
    ushort4 un = h4[(size_t)n * 64 + l];
    float4 bv = ((const float4*)b1)[l];
    float v0 = fmaxf(fmaf(sl, bf2f(un.x), acc.x) + bv.x, 0.f);
    float v1 = fmaxf(fmaf(sl, bf2f(un.y), acc.y) + bv.y, 0.f);
    float v2 = fmaxf(fmaf(sl, bf2f(un.z), acc.z) + bv.z, 0.f);
    float v3 = fmaxf(fmaf(sl, bf2f(un.w), acc.w) + bv.w, 0.f);
    uint32_t base = (uint32_t)n * D + (uint32_t)l * 4u;
    v0 = dropout_keep(base + 0u) ? v0 * 2.f : 0.f;
    v1 = dropout_keep(base + 1u) ? v1 * 2.f : 0.f;
    v2 = dropout_keep(base + 2u) ? v2 * 2.f : 0.f;
    v3 = dropout_keep(base + 3u) ? v3 * 2.f : 0.f;
    ((float4*)y)[(size_t)n * 64 + l] = make_float4(v0, v1, v2, v3);
}

// Fused segmented-mean pool + FC: one block per graph (index is sorted).
__global__ __launch_bounds__(256) void k_poolfinal(const float* __restrict__ y,
                                                   const int* __restrict__ gidx,
                                                   const float* __restrict__ fcW,
                                                   const float* __restrict__ fcb,
                                                   float* __restrict__ out) {
    __shared__ int sh[2];
    __shared__ float p[D];
    int g = blockIdx.x, t = threadIdx.x;
    if (t == 0) {
        int lo = 0, hi = N_NODES;
        while (lo < hi) { int m = (lo + hi) >> 1; if (gidx[m] < g) lo = m + 1; else hi = m; }
        sh[0] = lo;
        int lo2 = lo; hi = N_NODES;
        while (lo2 < hi) { int m = (lo2 + hi) >> 1; if (gidx[m] < g + 1) lo2 = m + 1; else hi = m; }
        sh[1] = lo2;
    }
    __syncthreads();
    int lo = sh[0], hi = sh[1];
    float s0 = 0.f, s1 = 0.f, s2 = 0.f, s3 = 0.f;
    float s4 = 0.f, s5 = 0.f, s6 = 0.f, s7 = 0.f;
    int r = lo;
    for (; r + 8 <= hi; r += 8) {
        s0 += y[(size_t)(r + 0) * D + t];
        s1 += y[(size_t)(r + 1) * D + t];
        s2 += y[(size_t)(r + 2) * D + t];
        s3 += y[(size_t)(r + 3) * D + t];
        s4 += y[(size_t)(r + 4) * D + t];
        s5 += y[(size_t)(r + 5) * D + t];
        s6 += y[(size_t)(r + 6) * D + t];
        s7 += y[(size_t)(r + 7) * D + t];
    }
    for (; r < hi; r++) s0 += y[(size_t)r * D + t];
    float s = ((s0 + s1) + (s2 + s3)) + ((s4 + s5) + (s6 + s7));
    float c = (float)(hi - lo);
    p[t] = s / fmaxf(c, 1.0f);
    __syncthreads();
    if (t < D_OUT) {
        float acc = fcb[t];
        for (int k = 0; k < D; k++)
            acc = fmaf(p[k], fcW[k * D_OUT + t], acc);
        out[g * D_OUT + t] = acc;
    }
}

extern "C" void kernel_launch(void* const* d_in, const int* in_sizes, int n_in,
                              void* d_out, int out_size, void* d_ws, size_t ws_size,
                              hipStream_t stream) {
    const float* x   = (const float*)d_in[0];
    const int*   ei  = (const int*)d_in[1];
    const float* ew  = (const float*)d_in[2];
    const int*   gix = (const int*)d_in[3];
    const float* W1  = (const float*)d_in[4];
    const float* b1  = (const float*)d_in[5];
    const float* fcW = (const float*)d_in[6];
    const float* fcb = (const float*)d_in[7];
    float* out = (float*)d_out;

    float*  ws     = (float*)d_ws;
    float*  dinv   = ws;                                  //     65,536 f
    ushort* hb     = (ushort*)(ws + 65536);               // 12.8M bf16 = 6.4M f
    int*    rows   = (int*)(ws + 65536 + 6400000);        //    800,000
    float*  wn     = (float*)(rows + N_EDGES);            //    800,000
    int*    start  = (int*)(wn + N_EDGES);                //     65,536
    int*    cursor = start + 65536;                       //     65,536
    int*    partial    = cursor + 65536;                  //        256
    int*    partialExc = partial + 256;                   //        256
    float*  y      = (float*)(partialExc + 256);          // 12,800,000
    // total ~21.0M floats = ~84 MB

    k_init<<<(N_NODES + 256) / 256, 256, 0, stream>>>(dinv, start);
    k_deg_hist<<<(N_EDGES + 255) / 256, 256, 0, stream>>>(ei, ew, dinv, start);
    k_scan1<<<NB_SCAN, 256, 0, stream>>>(dinv, start, partial);
    k_scan2<<<1, 256, 0, stream>>>(partial, partialExc);
    k_scan3<<<NB_SCAN, 256, 0, stream>>>(start, cursor, partialExc);
    k_fill<<<(N_EDGES + 255) / 256, 256, 0, stream>>>(ei, ew, dinv, cursor, rows, wn);
    dim3 ggrid((N_NODES + 63) / 64, 4);
    k_gemm<<<ggrid, 256, 0, stream>>>(x, W1, hb);
    k_agg<<<N_NODES / 4, 256, 0, stream>>>(start, rows, wn, hb, dinv, b1, y);
    k_poolfinal<<<N_GRAPHS, 256, 0, stream>>>(y, gix, fcW, fcb, out);
}

// Round 9
// 274.475 us; speedup vs baseline: 4.2205x; 1.0683x over previous
//
#include <hip/hip_runtime.h>
#include <stdint.h>

// Problem constants (match reference)
#define N_NODES  50000
#define N_EDGES  800000
#define D        256
#define D_OUT    16
#define N_GRAPHS 128
#define NB_SCAN  196        // 196*256 = 50176 >= N_NODES+1

// JAX jax_threefry_partitionable=True: bits32(i) = fold(threefry2x32((0,42),(0,i))),
// fold = o0 ^ o1; keep iff top bit == 0.  (verified round 2, absmax 0.0)

typedef short bf16x8 __attribute__((ext_vector_type(8)));
typedef float f32x4  __attribute__((ext_vector_type(4)));

__device__ __forceinline__ uint32_t rotl32(uint32_t x, int d) {
    return (x << d) | (x >> (32 - d));
}

__device__ __forceinline__ void threefry2x32(uint32_t k0, uint32_t k1,
                                             uint32_t c0, uint32_t c1,
                                             uint32_t& o0, uint32_t& o1) {
    uint32_t ks2 = k0 ^ k1 ^ 0x1BD11BDAu;
    uint32_t x0 = c0 + k0, x1 = c1 + k1;
    x0 += x1; x1 = rotl32(x1, 13); x1 ^= x0;
    x0 += x1; x1 = rotl32(x1, 15); x1 ^= x0;
    x0 += x1; x1 = rotl32(x1, 26); x1 ^= x0;
    x0 += x1; x1 = rotl32(x1, 6);  x1 ^= x0;
    x0 += k1; x1 += ks2 + 1u;
    x0 += x1; x1 = rotl32(x1, 17); x1 ^= x0;
    x0 += x1; x1 = rotl32(x1, 29); x1 ^= x0;
    x0 += x1; x1 = rotl32(x1, 16); x1 ^= x0;
    x0 += x1; x1 = rotl32(x1, 24); x1 ^= x0;
    x0 += ks2; x1 += k0 + 2u;
    x0 += x1; x1 = rotl32(x1, 13); x1 ^= x0;
    x0 += x1; x1 = rotl32(x1, 15); x1 ^= x0;
    x0 += x1; x1 = rotl32(x1, 26); x1 ^= x0;
    x0 += x1; x1 = rotl32(x1, 6);  x1 ^= x0;
    x0 += k0; x1 += k1 + 3u;
    x0 += x1; x1 = rotl32(x1, 17); x1 ^= x0;
    x0 += x1; x1 = rotl32(x1, 29); x1 ^= x0;
    x0 += x1; x1 = rotl32(x1, 16); x1 ^= x0;
    x0 += x1; x1 = rotl32(x1, 24); x1 ^= x0;
    x0 += k1; x1 += ks2 + 4u;
    x0 += x1; x1 = rotl32(x1, 13); x1 ^= x0;
    x0 += x1; x1 = rotl32(x1, 15); x1 ^= x0;
    x0 += x1; x1 = rotl32(x1, 26); x1 ^= x0;
    x0 += x1; x1 = rotl32(x1, 6);  x1 ^= x0;
    x0 += ks2; x1 += k0 + 5u;
    o0 = x0; o1 = x1;
}

__device__ __forceinline__ bool dropout_keep(uint32_t i) {
    uint32_t o0, o1;
    threefry2x32(0u, 42u, 0u, i, o0, o1);
    return ((o0 ^ o1) & 0x80000000u) == 0u;
}

__device__ __forceinline__ uint32_t bf16_rne(float f) {   // fp32 -> bf16 bits (RNE)
    uint32_t u = __float_as_uint(f);
    return (u + 0x7FFFu + ((u >> 16) & 1u)) >> 16;
}
__device__ __forceinline__ float bf2f(unsigned short u) {
    return __uint_as_float((uint32_t)u << 16);
}

// deg = 1 (self-loop), start = 0, sums = 0
__global__ __launch_bounds__(256) void k_init(float* deg, int* start, float* sums) {
    int i = blockIdx.x * 256 + threadIdx.x;
    if (i < N_NODES) deg[i] = 1.0f;
    if (i < N_NODES + 1) start[i] = 0;
    if (i < N_GRAPHS * D) sums[i] = 0.0f;
}

// W[k][n] f32 -> wt[n][k] bf16 (transposed, packed)
__global__ __launch_bounds__(256) void k_wt(const float* __restrict__ W,
                                            ushort* __restrict__ wt) {
    __shared__ float td[64][65];
    int kb = blockIdx.x, nb = blockIdx.y;    // 4x4 grid of 64x64 tiles
    int t = threadIdx.x;
    int nl = t & 63, r4 = t >> 6;
#pragma unroll
    for (int i = 0; i < 16; i++) {
        int kl = r4 + 4 * i;
        td[kl][nl] = W[(size_t)(kb * 64 + kl) * 256 + nb * 64 + nl];
    }
    __syncthreads();
    int kp = t & 31, nl2 = t >> 5;
    uint32_t* wt32 = (uint32_t*)wt;
#pragma unroll
    for (int i = 0; i < 8; i++) {
        int n = nl2 + 8 * i;
        uint32_t p = bf16_rne(td[2 * kp][n]) | (bf16_rne(td[2 * kp + 1][n]) << 16);
        wt32[((size_t)(nb * 64 + n) * 256 + kb * 64 + 2 * kp) >> 1] = p;
    }
}

// fused: weighted degree (float atomics) + target histogram (int atomics)
__global__ __launch_bounds__(256) void k_deg_hist(const int* __restrict__ ei,
                                                  const float* __restrict__ ew,
                                                  float* __restrict__ deg,
                                                  int* __restrict__ start) {
    int e = blockIdx.x * 256 + threadIdx.x;
    if (e < N_EDGES) {
        int c = ei[N_EDGES + e];
        atomicAdd(&deg[c], ew[e]);
        atomicAdd(&start[c], 1);
    }
}

// scan phase 1: coalesced dinv conversion + per-block reduce of start counts
__global__ __launch_bounds__(256) void k_scan1(float* __restrict__ deg,
                                               const int* __restrict__ start,
                                               int* __restrict__ partial) {
    __shared__ int sd[256];
    int t = threadIdx.x;
    int i = blockIdx.x * 256 + t;
    if (i < N_NODES) {
        float d = deg[i];
        deg[i] = (d > 0.0f) ? rsqrtf(d) : 0.0f;
    }
    int v = (i < N_NODES) ? start[i] : 0;
    sd[t] = v;
    __syncthreads();
    for (int d = 128; d > 0; d >>= 1) {
        if (t < d) sd[t] += sd[t + d];
        __syncthreads();
    }
    if (t == 0) partial[blockIdx.x] = sd[0];
}

// scan phase 2: single block exclusive-scans the NB_SCAN partials
__global__ __launch_bounds__(256) void k_scan2(int* __restrict__ partial,
                                               int* __restrict__ partialExc) {
    __shared__ int sd[256];
    int t = threadIdx.x;
    int v = (t < NB_SCAN) ? partial[t] : 0;
    sd[t] = v;
    __syncthreads();
    for (int d = 1; d < 256; d <<= 1) {
        int u = (t >= d) ? sd[t - d] : 0;
        __syncthreads();
        sd[t] += u;
        __syncthreads();
    }
    if (t < NB_SCAN) partialExc[t] = sd[t] - v;   // exclusive
    if (t == 255) partialExc[NB_SCAN] = sd[255];  // grand total
}

// scan phase 3: per-block LDS scan + base offset -> start/cursor (coalesced)
__global__ __launch_bounds__(256) void k_scan3(int* __restrict__ start,
                                               int* __restrict__ cursor,
                                               const int* __restrict__ partialExc) {
    __shared__ int sd[256];
    int t = threadIdx.x;
    int i = blockIdx.x * 256 + t;
    int v = (i < N_NODES) ? start[i] : 0;
    sd[t] = v;
    __syncthreads();
    for (int d = 1; d < 256; d <<= 1) {
        int u = (t >= d) ? sd[t - d] : 0;
        __syncthreads();
        sd[t] += u;
        __syncthreads();
    }
    int val = partialExc[blockIdx.x] + sd[t] - v;  // exclusive prefix
    if (i < N_NODES) {
        start[i] = val;
        cursor[i] = val;
    } else if (i == N_NODES) {
        start[N_NODES] = partialExc[NB_SCAN];
    }
}

// scatter each edge's (row, norm) into its CSR slot (single int2 store)
__global__ __launch_bounds__(256) void k_fill(const int* __restrict__ ei,
                                              const float* __restrict__ ew,
                                              const float* __restrict__ dinv,
                                              int* __restrict__ cursor,
                                              int2* __restrict__ edge) {
    int e = blockIdx.x * 256 + threadIdx.x;
    if (e < N_EDGES) {
        int r = ei[e];
        int c = ei[N_EDGES + e];
        int pos = atomicAdd(&cursor[c], 1);
        float nrm = dinv[r] * ew[e] * dinv[c];
        edge[pos] = make_int2(r, __float_as_int(nrm));
    }
}

// ---------------- MFMA GEMM: h(bf16) = x(f32->bf16) @ W1(bf16, pre-T) ------
// Block: 64 nodes x full 256 cols (N-loop internal). A staged once (32 KB),
// Bt streamed per 64-col tile from wt (32 KB). XOR swizzle on both.
__device__ __forceinline__ int swz(int row, int kByte) {
    return (row << 9) + (kByte ^ ((row & 7) << 4));
}

__global__ __launch_bounds__(256) void k_gemm(const float* __restrict__ x,
                                              const ushort* __restrict__ wt,
                                              ushort* __restrict__ hb) {
    __shared__ __align__(16) char smem[65536];   // A: [0,32K), Bt: [32K,64K)
    int tid = threadIdx.x;
    int Mbase = blockIdx.x * 64;

    // ---- stage A: x[Mbase..+63][0..255] -> bf16, swizzled ----
    const float4* xv = (const float4*)x;
#pragma unroll
    for (int i = 0; i < 16; i++) {
        int f = tid + i * 256;        // flat float4 id, 0..4095
        int r = f >> 6;               // row 0..63
        int c4 = f & 63;              // float4 index -> k = 4*c4
        int node = Mbase + r; if (node >= N_NODES) node = N_NODES - 1;
        float4 v = xv[(size_t)node * 64 + c4];
        uint32_t p0 = bf16_rne(v.x) | (bf16_rne(v.y) << 16);
        uint32_t p1 = bf16_rne(v.z) | (bf16_rne(v.w) << 16);
        *(uint2*)(smem + swz(r, c4 * 8)) = make_uint2(p0, p1);
    }

    int l = tid & 63;
    int w = tid >> 6;
    int wr = w >> 1, wc = w & 1;          // wave grid 2x2, each 32x32
    int lr = l & 15;
    int kg = l >> 4;
    int drow = (l >> 4) * 4;
    int dcol = l & 15;
    const uint4* wt4 = (const uint4*)wt;  // 16B units; 32 per 512B row

    for (int nb = 0; nb < 4; nb++) {
        // ---- stage Bt tile: wt rows nb*64..+63 (coalesced uint4 copy) ----
#pragma unroll
        for (int i = 0; i < 8; i++) {
            int f = tid + i * 256;    // 0..2047 uint4
            int r = f >> 5;           // row 0..63
            int c = f & 31;           // 16B chunk
            uint4 v = wt4[(size_t)(nb * 64 + r) * 32 + c];
            *(uint4*)(smem + 32768 + swz(r, c * 16)) = v;
        }
        __syncthreads();

        f32x4 acc00 = {0.f, 0.f, 0.f, 0.f};
        f32x4 acc01 = acc00, acc10 = acc00, acc11 = acc00;
#pragma unroll
        for (int ks = 0; ks < 8; ks++) {
            int kB = ks * 64 + kg * 16;
            bf16x8 a0 = *(const bf16x8*)(smem + swz(wr * 32 + lr, kB));
            bf16x8 a1 = *(const bf16x8*)(smem + swz(wr * 32 + 16 + lr, kB));
            bf16x8 b0 = *(const bf16x8*)(smem + 32768 + swz(wc * 32 + lr, kB));
            bf16x8 b1 = *(const bf16x8*)(smem + 32768 + swz(wc * 32 + 16 + lr, kB));
            acc00 = __builtin_amdgcn_mfma_f32_16x16x32_bf16(a0, b0, acc00, 0, 0, 0);
            acc01 = __builtin_amdgcn_mfma_f32_16x16x32_bf16(a0, b1, acc01, 0, 0, 0);
            acc10 = __builtin_amdgcn_mfma_f32_16x16x32_bf16(a1, b0, acc10, 0, 0, 0);
            acc11 = __builtin_amdgcn_mfma_f32_16x16x32_bf16(a1, b1, acc11, 0, 0, 0);
        }
        // D layout: row=(l>>4)*4+r, col=l&15  (m89-verified)
        int c0 = nb * 64 + wc * 32 + dcol;
#pragma unroll
        for (int r = 0; r < 4; r++) {
            int n0 = Mbase + wr * 32 + drow + r;
            int n1 = n0 + 16;
            if (n0 < N_NODES) {
                hb[(size_t)n0 * 256 + c0]      = (ushort)bf16_rne(acc00[r]);
                hb[(size_t)n0 * 256 + c0 + 16] = (ushort)bf16_rne(acc01[r]);
            }
            if (n1 < N_NODES) {
                hb[(size_t)n1 * 256 + c0]      = (ushort)bf16_rne(acc10[r]);
                hb[(size_t)n1 * 256 + c0 + 16] = (ushort)bf16_rne(acc11[r]);
            }
        }
        __syncthreads();   // Bt reused next iter
    }
}

// CSR aggregate + self-loop + bias + ReLU + dropout + fused pool-sum.
// One wave per 8 consecutive nodes (sorted graph ids); per-graph register
// accumulator flushed via atomicAdd only on graph change (~1 flush/wave).
__global__ __launch_bounds__(256) void k_agg(const int* __restrict__ start,
                                             const int2* __restrict__ edge,
                                             const ushort* __restrict__ hb,
                                             const float* __restrict__ dinv,
                                             const float* __restrict__ b1,
                                             const int* __restrict__ gidx,
                                             float* __restrict__ sums) {
    int wid = threadIdx.x >> 6;
    int l = threadIdx.x & 63;
    int nodeBase = (blockIdx.x * 4 + wid) * 8;
    if (nodeBase >= N_NODES) return;
    const ushort4* h4 = (const ushort4*)hb;
    float4 bv = ((const float4*)b1)[l];
    float4 gacc = make_float4(0.f, 0.f, 0.f, 0.f);
    int cur_g = gidx[nodeBase];

    for (int i = 0; i < 8; i++) {
        int n = nodeBase + i;
        if (n >= N_NODES) break;
        int s = start[n], e = start[n + 1];
        float4 a0 = make_float4(0.f, 0.f, 0.f, 0.f);
        float4 a1 = a0, a2 = a0, a3 = a0, a4 = a0, a5 = a0, a6 = a0, a7 = a0;
        int j = s;
        for (; j + 8 <= e; j += 8) {
            int2 e0 = edge[j],   e1 = edge[j+1], e2 = edge[j+2], e3 = edge[j+3];
            int2 e4 = edge[j+4], e5 = edge[j+5], e6 = edge[j+6], e7 = edge[j+7];
            ushort4 u0 = h4[(size_t)e0.x * 64 + l];
            ushort4 u1 = h4[(size_t)e1.x * 64 + l];
            ushort4 u2 = h4[(size_t)e2.x * 64 + l];
            ushort4 u3 = h4[(size_t)e3.x * 64 + l];
            ushort4 u4 = h4[(size_t)e4.x * 64 + l];
            ushort4 u5 = h4[(size_t)e5.x * 64 + l];
            ushort4 u6 = h4[(size_t)e6.x * 64 + l];
            ushort4 u7 = h4[(size_t)e7.x * 64 + l];
            float w0 = __int_as_float(e0.y), w1 = __int_as_float(e1.y);
            float w2 = __int_as_float(e2.y), w3 = __int_as_float(e3.y);
            float w4 = __int_as_float(e4.y), w5 = __int_as_float(e5.y);
            float w6 = __int_as_float(e6.y), w7 = __int_as_float(e7.y);
            a0.x = fmaf(w0, bf2f(u0.x), a0.x); a0.y = fmaf(w0, bf2f(u0.y), a0.y);
            a0.z = fmaf(w0, bf2f(u0.z), a0.z); a0.w = fmaf(w0, bf2f(u0.w), a0.w);
            a1.x = fmaf(w1, bf2f(u1.x), a1.x); a1.y = fmaf(w1, bf2f(u1.y), a1.y);
            a1.z = fmaf(w1, bf2f(u1.z), a1.z); a1.w = fmaf(w1, bf2f(u1.w), a1.w);
            a2.x = fmaf(w2, bf2f(u2.x), a2.x); a2.y = fmaf(w2, bf2f(u2.y), a2.y);
            a2.z = fmaf(w2, bf2f(u2.z), a2.z); a2.w = fmaf(w2, bf2f(u2.w), a2.w);
            a3.x = fmaf(w3, bf2f(u3.x), a3.x); a3.y = fmaf(w3, bf2f(u3.y), a3.y);
            a3.z = fmaf(w3, bf2f(u3.z), a3.z); a3.w = fmaf(w3, bf2f(u3.w), a3.w);
            a4.x = fmaf(w4, bf2f(u4.x), a4.x); a4.y = fmaf(w4, bf2f(u4.y), a4.y);
            a4.z = fmaf(w4, bf2f(u4.z), a4.z); a4.w = fmaf(w4, bf2f(u4.w), a4.w);
            a5.x = fmaf(w5, bf2f(u5.x), a5.x); a5.y = fmaf(w5, bf2f(u5.y), a5.y);
            a5.z = fmaf(w5, bf2f(u5.z), a5.z); a5.w = fmaf(w5, bf2f(u5.w), a5.w);
            a6.x = fmaf(w6, bf2f(u6.x), a6.x); a6.y = fmaf(w6, bf2f(u6.y), a6.y);
            a6.z = fmaf(w6, bf2f(u6.z), a6.z); a6.w = fmaf(w6, bf2f(u6.w), a6.w);
            a7.x = fmaf(w7, bf2f(u7.x), a7.x); a7.y = fmaf(w7, bf2f(u7.y), a7.y);
            a7.z = fmaf(w7, bf2f(u7.z), a7.z); a7.w = fmaf(w7, bf2f(u7.w), a7.w);
        }
        for (; j < e; j++) {
            int2 ee = edge[j];
            float w = __int_as_float(ee.y);
            ushort4 uv = h4[(size_t)ee.x * 64 + l];
            a0.x = fmaf(w, bf2f(uv.x), a0.x); a0.y = fmaf(w, bf2f(uv.y), a0.y);
            a0.z = fmaf(w, bf2f(uv.z), a0.z); a0.w = fmaf(w, bf2f(uv.w), a0.w);
        }
        float accx = ((a0.x + a1.x) + (a2.x + a3.x)) + ((a4.x + a5.x) + (a6.x + a7.x));
        float accy = ((a0.y + a1.y) + (a2.y + a3.y)) + ((a4.y + a5.y) + (a6.y + a7.y));
        float accz = ((a0.z + a1.z) + (a2.z + a3.z)) + ((a4.z + a5.z) + (a6.z + a7.z));
        float accw = ((a0.w + a1.w) + (a2.w + a3.w)) + ((a4.w + a5.w) + (a6.w + a7.w));
        float di = dinv[n];
        float sl = di * di;
        ushort4 un = h4[(size_t)n * 64 + l];
        float v0 = fmaxf(fmaf(sl, bf2f(un.x), accx) + bv.x, 0.f);
        float v1 = fmaxf(fmaf(sl, bf2f(un.y), accy) + bv.y, 0.f);
        float v2 = fmaxf(fmaf(sl, bf2f(un.z), accz) + bv.z, 0.f);
        float v3 = fmaxf(fmaf(sl, bf2f(un.w), accw) + bv.w, 0.f);
        uint32_t base = (uint32_t)n * D + (uint32_t)l * 4u;
        v0 = dropout_keep(base + 0u) ? v0 * 2.f : 0.f;
        v1 = dropout_keep(base + 1u) ? v1 * 2.f : 0.f;
        v2 = dropout_keep(base + 2u) ? v2 * 2.f : 0.f;
        v3 = dropout_keep(base + 3u) ? v3 * 2.f : 0.f;
        int g = gidx[n];
        if (g != cur_g) {
            float* sg = &sums[(size_t)cur_g * D + (size_t)l * 4];
            atomicAdd(sg + 0, gacc.x);
            atomicAdd(sg + 1, gacc.y);
            atomicAdd(sg + 2, gacc.z);
            atomicAdd(sg + 3, gacc.w);
            gacc = make_float4(0.f, 0.f, 0.f, 0.f);
            cur_g = g;
        }
        gacc.x += v0; gacc.y += v1; gacc.z += v2; gacc.w += v3;
    }
    float* sg = &sums[(size_t)cur_g * D + (size_t)l * 4];
    atomicAdd(sg + 0, gacc.x);
    atomicAdd(sg + 1, gacc.y);
    atomicAdd(sg + 2, gacc.z);
    atomicAdd(sg + 3, gacc.w);
}

// pooled = sums/cnt (cnt via binary search on sorted gidx); out = pooled@fcW+fcb
__global__ __launch_bounds__(256) void k_out(const float* __restrict__ sums,
                                             const int* __restrict__ gidx,
                                             const float* __restrict__ fcW,
                                             const float* __restrict__ fcb,
                                             float* __restrict__ out) {
    __shared__ int sh[2];
    __shared__ float p[D];
    int g = blockIdx.x, t = threadIdx.x;
    if (t == 0) {
        int lo = 0, hi = N_NODES;
        while (lo < hi) { int m = (lo + hi) >> 1; if (gidx[m] < g) lo = m + 1; else hi = m; }
        sh[0] = lo;
        int lo2 = lo; hi = N_NODES;
        while (lo2 < hi) { int m = (lo2 + hi) >> 1; if (gidx[m] < g + 1) lo2 = m + 1; else hi = m; }
        sh[1] = lo2;
    }
    __syncthreads();
    float c = fmaxf((float)(sh[1] - sh[0]), 1.0f);
    p[t] = sums[(size_t)g * D + t] / c;
    __syncthreads();
    if (t < D_OUT) {
        float acc = fcb[t];
        for (int k = 0; k < D; k++)
            acc = fmaf(p[k], fcW[k * D_OUT + t], acc);
        out[g * D_OUT + t] = acc;
    }
}

extern "C" void kernel_launch(void* const* d_in, const int* in_sizes, int n_in,
                              void* d_out, int out_size, void* d_ws, size_t ws_size,
                              hipStream_t stream) {
    const float* x   = (const float*)d_in[0];
    const int*   ei  = (const int*)d_in[1];
    const float* ew  = (const float*)d_in[2];
    const int*   gix = (const int*)d_in[3];
    const float* W1  = (const float*)d_in[4];
    const float* b1  = (const float*)d_in[5];
    const float* fcW = (const float*)d_in[6];
    const float* fcb = (const float*)d_in[7];
    float* out = (float*)d_out;

    float*  ws     = (float*)d_ws;
    float*  dinv   = ws;                                  //    65,536 f
    ushort* hb     = (ushort*)(ws + 65536);               // 12.8M bf16 = 6.4M f
    int2*   edge   = (int2*)(ws + 65536 + 6400000);       //   800,000 int2 = 1.6M f
    int*    start  = (int*)(edge + N_EDGES);              //    65,536
    int*    cursor = start + 65536;                       //    65,536
    int*    partial    = cursor + 65536;                  //       256
    int*    partialExc = partial + 256;                   //       512 (pad)
    ushort* wt     = (ushort*)(partialExc + 512);         //    65,536 us = 32,768 f
    float*  sums   = (float*)(wt + 65536);                //    32,768 f
    // total ~8.3M floats = ~33 MB

    k_init<<<NB_SCAN, 256, 0, stream>>>(dinv, start, sums);
    k_wt<<<dim3(4, 4), 256, 0, stream>>>(W1, wt);
    k_deg_hist<<<(N_EDGES + 255) / 256, 256, 0, stream>>>(ei, ew, dinv, start);
    k_scan1<<<NB_SCAN, 256, 0, stream>>>(dinv, start, partial);
    k_scan2<<<1, 256, 0, stream>>>(partial, partialExc);
    k_scan3<<<NB_SCAN, 256, 0, stream>>>(start, cursor, partialExc);
    k_fill<<<(N_EDGES + 255) / 256, 256, 0, stream>>>(ei, ew, dinv, cursor, edge);
    k_gemm<<<(N_NODES + 63) / 64, 256, 0, stream>>>(x, wt, hb);
    k_agg<<<(N_NODES + 31) / 32, 256, 0, stream>>>(start, edge, hb, dinv, b1, gix, sums);
    k_out<<<N_GRAPHS, 256, 0, stream>>>(sums, gix, fcW, fcb, out);
}

// Round 10
// 255.595 us; speedup vs baseline: 4.5322x; 1.0739x over previous
//
#include <hip/hip_runtime.h>
#include <stdint.h>

// Problem constants (match reference)
#define N_NODES  50000
#define N_EDGES  800000
#define D        256
#define D_OUT    16
#define N_GRAPHS 128
#define NB_SCAN  196        // 196*256 = 50176 >= N_NODES+1

// JAX jax_threefry_partitionable=True: bits32(i) = fold(threefry2x32((0,42),(0,i))),
// fold = o0 ^ o1; keep iff top bit == 0.  (verified round 2, absmax 0.0)

typedef short bf16x8 __attribute__((ext_vector_type(8)));
typedef float f32x4  __attribute__((ext_vector_type(4)));

__device__ __forceinline__ uint32_t rotl32(uint32_t x, int d) {
    return (x << d) | (x >> (32 - d));
}

__device__ __forceinline__ void threefry2x32(uint32_t k0, uint32_t k1,
                                             uint32_t c0, uint32_t c1,
                                             uint32_t& o0, uint32_t& o1) {
    uint32_t ks2 = k0 ^ k1 ^ 0x1BD11BDAu;
    uint32_t x0 = c0 + k0, x1 = c1 + k1;
    x0 += x1; x1 = rotl32(x1, 13); x1 ^= x0;
    x0 += x1; x1 = rotl32(x1, 15); x1 ^= x0;
    x0 += x1; x1 = rotl32(x1, 26); x1 ^= x0;
    x0 += x1; x1 = rotl32(x1, 6);  x1 ^= x0;
    x0 += k1; x1 += ks2 + 1u;
    x0 += x1; x1 = rotl32(x1, 17); x1 ^= x0;
    x0 += x1; x1 = rotl32(x1, 29); x1 ^= x0;
    x0 += x1; x1 = rotl32(x1, 16); x1 ^= x0;
    x0 += x1; x1 = rotl32(x1, 24); x1 ^= x0;
    x0 += ks2; x1 += k0 + 2u;
    x0 += x1; x1 = rotl32(x1, 13); x1 ^= x0;
    x0 += x1; x1 = rotl32(x1, 15); x1 ^= x0;
    x0 += x1; x1 = rotl32(x1, 26); x1 ^= x0;
    x0 += x1; x1 = rotl32(x1, 6);  x1 ^= x0;
    x0 += k0; x1 += k1 + 3u;
    x0 += x1; x1 = rotl32(x1, 17); x1 ^= x0;
    x0 += x1; x1 = rotl32(x1, 29); x1 ^= x0;
    x0 += x1; x1 = rotl32(x1, 16); x1 ^= x0;
    x0 += x1; x1 = rotl32(x1, 24); x1 ^= x0;
    x0 += k1; x1 += ks2 + 4u;
    x0 += x1; x1 = rotl32(x1, 13); x1 ^= x0;
    x0 += x1; x1 = rotl32(x1, 15); x1 ^= x0;
    x0 += x1; x1 = rotl32(x1, 26); x1 ^= x0;
    x0 += x1; x1 = rotl32(x1, 6);  x1 ^= x0;
    x0 += ks2; x1 += k0 + 5u;
    o0 = x0; o1 = x1;
}

__device__ __forceinline__ bool dropout_keep(uint32_t i) {
    uint32_t o0, o1;
    threefry2x32(0u, 42u, 0u, i, o0, o1);
    return ((o0 ^ o1) & 0x80000000u) == 0u;
}

__device__ __forceinline__ uint32_t bf16_rne(float f) {   // fp32 -> bf16 bits (RNE)
    uint32_t u = __float_as_uint(f);
    return (u + 0x7FFFu + ((u >> 16) & 1u)) >> 16;
}
__device__ __forceinline__ float bf2f(unsigned short u) {
    return __uint_as_float((uint32_t)u << 16);
}

// blocks 0..15: W[k][n] f32 -> wt[n][k] bf16 (transposed, packed)
// blocks 16..: deg = 1 (self-loop), start = 0, sums = 0
__global__ __launch_bounds__(256) void k_init(const float* __restrict__ W,
                                              ushort* __restrict__ wt,
                                              float* deg, int* start, float* sums) {
    int t = threadIdx.x;
    if (blockIdx.x < 16) {
        __shared__ float td[64][65];
        int kb = blockIdx.x & 3, nb = blockIdx.x >> 2;   // 4x4 tiles of 64x64
        int nl = t & 63, r4 = t >> 6;
#pragma unroll
        for (int i = 0; i < 16; i++) {
            int kl = r4 + 4 * i;
            td[kl][nl] = W[(size_t)(kb * 64 + kl) * 256 + nb * 64 + nl];
        }
        __syncthreads();
        int kp = t & 31, nl2 = t >> 5;
        uint32_t* wt32 = (uint32_t*)wt;
#pragma unroll
        for (int i = 0; i < 8; i++) {
            int n = nl2 + 8 * i;
            uint32_t p = bf16_rne(td[2 * kp][n]) | (bf16_rne(td[2 * kp + 1][n]) << 16);
            wt32[((size_t)(nb * 64 + n) * 256 + kb * 64 + 2 * kp) >> 1] = p;
        }
    } else {
        int i = (blockIdx.x - 16) * 256 + t;
        if (i < N_NODES) deg[i] = 1.0f;
        if (i < N_NODES + 1) start[i] = 0;
        if (i < N_GRAPHS * D) sums[i] = 0.0f;
    }
}

// fused: weighted degree (float atomics) + target histogram (int atomics)
__global__ __launch_bounds__(256) void k_deg_hist(const int* __restrict__ ei,
                                                  const float* __restrict__ ew,
                                                  float* __restrict__ deg,
                                                  int* __restrict__ start) {
    int e = blockIdx.x * 256 + threadIdx.x;
    if (e < N_EDGES) {
        int c = ei[N_EDGES + e];
        atomicAdd(&deg[c], ew[e]);
        atomicAdd(&start[c], 1);
    }
}

// scan phase 1: coalesced dinv conversion + per-block reduce of start counts
__global__ __launch_bounds__(256) void k_scan1(float* __restrict__ deg,
                                               const int* __restrict__ start,
                                               int* __restrict__ partial) {
    __shared__ int sd[256];
    int t = threadIdx.x;
    int i = blockIdx.x * 256 + t;
    if (i < N_NODES) {
        float d = deg[i];
        deg[i] = (d > 0.0f) ? rsqrtf(d) : 0.0f;
    }
    int v = (i < N_NODES) ? start[i] : 0;
    sd[t] = v;
    __syncthreads();
    for (int d = 128; d > 0; d >>= 1) {
        if (t < d) sd[t] += sd[t + d];
        __syncthreads();
    }
    if (t == 0) partial[blockIdx.x] = sd[0];
}

// scan phase 2: single block exclusive-scans the NB_SCAN partials
__global__ __launch_bounds__(256) void k_scan2(int* __restrict__ partial,
                                               int* __restrict__ partialExc) {
    __shared__ int sd[256];
    int t = threadIdx.x;
    int v = (t < NB_SCAN) ? partial[t] : 0;
    sd[t] = v;
    __syncthreads();
    for (int d = 1; d < 256; d <<= 1) {
        int u = (t >= d) ? sd[t - d] : 0;
        __syncthreads();
        sd[t] += u;
        __syncthreads();
    }
    if (t < NB_SCAN) partialExc[t] = sd[t] - v;   // exclusive
    if (t == 255) partialExc[NB_SCAN] = sd[255];  // grand total
}

// scan phase 3: per-block LDS scan + base offset -> start/cursor (coalesced)
__global__ __launch_bounds__(256) void k_scan3(int* __restrict__ start,
                                               int* __restrict__ cursor,
                                               const int* __restrict__ partialExc) {
    __shared__ int sd[256];
    int t = threadIdx.x;
    int i = blockIdx.x * 256 + t;
    int v = (i < N_NODES) ? start[i] : 0;
    sd[t] = v;
    __syncthreads();
    for (int d = 1; d < 256; d <<= 1) {
        int u = (t >= d) ? sd[t - d] : 0;
        __syncthreads();
        sd[t] += u;
        __syncthreads();
    }
    int val = partialExc[blockIdx.x] + sd[t] - v;  // exclusive prefix
    if (i < N_NODES) {
        start[i] = val;
        cursor[i] = val;
    } else if (i == N_NODES) {
        start[N_NODES] = partialExc[NB_SCAN];
    }
}

// scatter each edge's (row, norm) into its CSR slot (single int2 store)
__global__ __launch_bounds__(256) void k_fill(const int* __restrict__ ei,
                                              const float* __restrict__ ew,
                                              const float* __restrict__ dinv,
                                              int* __restrict__ cursor,
                                              int2* __restrict__ edge) {
    int e = blockIdx.x * 256 + threadIdx.x;
    if (e < N_EDGES) {
        int r = ei[e];
        int c = ei[N_EDGES + e];
        int pos = atomicAdd(&cursor[c], 1);
        float nrm = dinv[r] * ew[e] * dinv[c];
        edge[pos] = make_int2(r, __float_as_int(nrm));
    }
}

// ---------------- MFMA GEMM: h(bf16) = x(f32->bf16) @ W1(bf16, pre-T) ------
__device__ __forceinline__ int swz(int row, int kByte) {
    return (row << 9) + (kByte ^ ((row & 7) << 4));
}

__global__ __launch_bounds__(256) void k_gemm(const float* __restrict__ x,
                                              const ushort* __restrict__ wt,
                                              ushort* __restrict__ hb) {
    __shared__ __align__(16) char smem[65536];   // A: [0,32K), Bt: [32K,64K)
    int tid = threadIdx.x;
    int Mbase = blockIdx.x * 64;

    // ---- stage A: x[Mbase..+63][0..255] -> bf16, swizzled ----
    const float4* xv = (const float4*)x;
#pragma unroll
    for (int i = 0; i < 16; i++) {
        int f = tid + i * 256;        // flat float4 id, 0..4095
        int r = f >> 6;               // row 0..63
        int c4 = f & 63;              // float4 index -> k = 4*c4
        int node = Mbase + r; if (node >= N_NODES) node = N_NODES - 1;
        float4 v = xv[(size_t)node * 64 + c4];
        uint32_t p0 = bf16_rne(v.x) | (bf16_rne(v.y) << 16);
        uint32_t p1 = bf16_rne(v.z) | (bf16_rne(v.w) << 16);
        *(uint2*)(smem + swz(r, c4 * 8)) = make_uint2(p0, p1);
    }

    int l = tid & 63;
    int w = tid >> 6;
    int wr = w >> 1, wc = w & 1;          // wave grid 2x2, each 32x32
    int lr = l & 15;
    int kg = l >> 4;
    int drow = (l >> 4) * 4;
    int dcol = l & 15;
    const uint4* wt4 = (const uint4*)wt;  // 16B units; 32 per 512B row

    for (int nb = 0; nb < 4; nb++) {
        // ---- stage Bt tile: wt rows nb*64..+63 (coalesced uint4 copy) ----
#pragma unroll
        for (int i = 0; i < 8; i++) {
            int f = tid + i * 256;    // 0..2047 uint4
            int r = f >> 5;           // row 0..63
            int c = f & 31;           // 16B chunk
            uint4 v = wt4[(size_t)(nb * 64 + r) * 32 + c];
            *(uint4*)(smem + 32768 + swz(r, c * 16)) = v;
        }
        __syncthreads();

        f32x4 acc00 = {0.f, 0.f, 0.f, 0.f};
        f32x4 acc01 = acc00, acc10 = acc00, acc11 = acc00;
#pragma unroll
        for (int ks = 0; ks < 8; ks++) {
            int kB = ks * 64 + kg * 16;
            bf16x8 a0 = *(const bf16x8*)(smem + swz(wr * 32 + lr, kB));
            bf16x8 a1 = *(const bf16x8*)(smem + swz(wr * 32 + 16 + lr, kB));
            bf16x8 b0 = *(const bf16x8*)(smem + 32768 + swz(wc * 32 + lr, kB));
            bf16x8 b1 = *(const bf16x8*)(smem + 32768 + swz(wc * 32 + 16 + lr, kB));
            acc00 = __builtin_amdgcn_mfma_f32_16x16x32_bf16(a0, b0, acc00, 0, 0, 0);
            acc01 = __builtin_amdgcn_mfma_f32_16x16x32_bf16(a0, b1, acc01, 0, 0, 0);
            acc10 = __builtin_amdgcn_mfma_f32_16x16x32_bf16(a1, b0, acc10, 0, 0, 0);
            acc11 = __builtin_amdgcn_mfma_f32_16x16x32_bf16(a1, b1, acc11, 0, 0, 0);
        }
        // D layout: row=(l>>4)*4+r, col=l&15  (m89-verified)
        int c0 = nb * 64 + wc * 32 + dcol;
#pragma unroll
        for (int r = 0; r < 4; r++) {
            int n0 = Mbase + wr * 32 + drow + r;
            int n1 = n0 + 16;
            if (n0 < N_NODES) {
                hb[(size_t)n0 * 256 + c0]      = (ushort)bf16_rne(acc00[r]);
                hb[(size_t)n0 * 256 + c0 + 16] = (ushort)bf16_rne(acc01[r]);
            }
            if (n1 < N_NODES) {
                hb[(size_t)n1 * 256 + c0]      = (ushort)bf16_rne(acc10[r]);
                hb[(size_t)n1 * 256 + c0 + 16] = (ushort)bf16_rne(acc11[r]);
            }
        }
        __syncthreads();   // Bt reused next iter
    }
}

// CSR aggregate + self-loop + bias + ReLU + dropout + block-level LDS pool.
// One wave per node (4 nodes/block, 50000 waves). Uniform-graph blocks do a
// single LDS-combined flush (1 atomic/thread); boundary blocks flush per-wave.
__global__ __launch_bounds__(256) void k_agg(const int* __restrict__ start,
                                             const int2* __restrict__ edge,
                                             const ushort* __restrict__ hb,
                                             const float* __restrict__ dinv,
                                             const float* __restrict__ b1,
                                             const int* __restrict__ gidx,
                                             float* __restrict__ sums) {
    __shared__ float ls[4][256];
    int wid = threadIdx.x >> 6;
    int l = threadIdx.x & 63;
    int n = blockIdx.x * 4 + wid;          // always < N_NODES (12500*4)
    const ushort4* h4 = (const ushort4*)hb;
    int s = start[n], e = start[n + 1];
    float4 a0 = make_float4(0.f, 0.f, 0.f, 0.f);
    float4 a1 = a0, a2 = a0, a3 = a0, a4 = a0, a5 = a0, a6 = a0, a7 = a0;
    int j = s;
    for (; j + 8 <= e; j += 8) {
        int2 e0 = edge[j],   e1 = edge[j+1], e2 = edge[j+2], e3 = edge[j+3];
        int2 e4 = edge[j+4], e5 = edge[j+5], e6 = edge[j+6], e7 = edge[j+7];
        ushort4 u0 = h4[(size_t)e0.x * 64 + l];
        ushort4 u1 = h4[(size_t)e1.x * 64 + l];
        ushort4 u2 = h4[(size_t)e2.x * 64 + l];
        ushort4 u3 = h4[(size_t)e3.x * 64 + l];
        ushort4 u4 = h4[(size_t)e4.x * 64 + l];
        ushort4 u5 = h4[(size_t)e5.x * 64 + l];
        ushort4 u6 = h4[(size_t)e6.x * 64 + l];
        ushort4 u7 = h4[(size_t)e7.x * 64 + l];
        float w0 = __int_as_float(e0.y), w1 = __int_as_float(e1.y);
        float w2 = __int_as_float(e2.y), w3 = __int_as_float(e3.y);
        float w4 = __int_as_float(e4.y), w5 = __int_as_float(e5.y);
        float w6 = __int_as_float(e6.y), w7 = __int_as_float(e7.y);
        a0.x = fmaf(w0, bf2f(u0.x), a0.x); a0.y = fmaf(w0, bf2f(u0.y), a0.y);
        a0.z = fmaf(w0, bf2f(u0.z), a0.z); a0.w = fmaf(w0, bf2f(u0.w), a0.w);
        a1.x = fmaf(w1, bf2f(u1.x), a1.x); a1.y = fmaf(w1, bf2f(u1.y), a1.y);
        a1.z = fmaf(w1, bf2f(u1.z), a1.z); a1.w = fmaf(w1, bf2f(u1.w), a1.w);
        a2.x = fmaf(w2, bf2f(u2.x), a2.x); a2.y = fmaf(w2, bf2f(u2.y), a2.y);
        a2.z = fmaf(w2, bf2f(u2.z), a2.z); a2.w = fmaf(w2, bf2f(u2.w), a2.w);
        a3.x = fmaf(w3, bf2f(u3.x), a3.x); a3.y = fmaf(w3, bf2f(u3.y), a3.y);
        a3.z = fmaf(w3, bf2f(u3.z), a3.z); a3.w = fmaf(w3, bf2f(u3.w), a3.w);
        a4.x = fmaf(w4, bf2f(u4.x), a4.x); a4.y = fmaf(w4, bf2f(u4.y), a4.y);
        a4.z = fmaf(w4, bf2f(u4.z), a4.z); a4.w = fmaf(w4, bf2f(u4.w), a4.w);
        a5.x = fmaf(w5, bf2f(u5.x), a5.x); a5.y = fmaf(w5, bf2f(u5.y), a5.y);
        a5.z = fmaf(w5, bf2f(u5.z), a5.z); a5.w = fmaf(w5, bf2f(u5.w), a5.w);
        a6.x = fmaf(w6, bf2f(u6.x), a6.x); a6.y = fmaf(w6, bf2f(u6.y), a6.y);
        a6.z = fmaf(w6, bf2f(u6.z), a6.z); a6.w = fmaf(w6, bf2f(u6.w), a6.w);
        a7.x = fmaf(w7, bf2f(u7.x), a7.x); a7.y = fmaf(w7, bf2f(u7.y), a7.y);
        a7.z = fmaf(w7, bf2f(u7.z), a7.z); a7.w = fmaf(w7, bf2f(u7.w), a7.w);
    }
    for (; j < e; j++) {
        int2 ee = edge[j];
        float w = __int_as_float(ee.y);
        ushort4 uv = h4[(size_t)ee.x * 64 + l];
        a0.x = fmaf(w, bf2f(uv.x), a0.x); a0.y = fmaf(w, bf2f(uv.y), a0.y);
        a0.z = fmaf(w, bf2f(uv.z), a0.z); a0.w = fmaf(w, bf2f(uv.w), a0.w);
    }
    float accx = ((a0.x + a1.x) + (a2.x + a3.x)) + ((a4.x + a5.x) + (a6.x + a7.x));
    float accy = ((a0.y + a1.y) + (a2.y + a3.y)) + ((a4.y + a5.y) + (a6.y + a7.y));
    float accz = ((a0.z + a1.z) + (a2.z + a3.z)) + ((a4.z + a5.z) + (a6.z + a7.z));
    float accw = ((a0.w + a1.w) + (a2.w + a3.w)) + ((a4.w + a5.w) + (a6.w + a7.w));
    float di = dinv[n];
    float sl = di * di;
    ushort4 un = h4[(size_t)n * 64 + l];
    float4 bv = ((const float4*)b1)[l];
    float v0 = fmaxf(fmaf(sl, bf2f(un.x), accx) + bv.x, 0.f);
    float v1 = fmaxf(fmaf(sl, bf2f(un.y), accy) + bv.y, 0.f);
    float v2 = fmaxf(fmaf(sl, bf2f(un.z), accz) + bv.z, 0.f);
    float v3 = fmaxf(fmaf(sl, bf2f(un.w), accw) + bv.w, 0.f);
    uint32_t base = (uint32_t)n * D + (uint32_t)l * 4u;
    v0 = dropout_keep(base + 0u) ? v0 * 2.f : 0.f;
    v1 = dropout_keep(base + 1u) ? v1 * 2.f : 0.f;
    v2 = dropout_keep(base + 2u) ? v2 * 2.f : 0.f;
    v3 = dropout_keep(base + 3u) ? v3 * 2.f : 0.f;

    int gfirst = gidx[blockIdx.x * 4];
    int glast  = gidx[blockIdx.x * 4 + 3];
    if (gfirst == glast) {                 // block-uniform branch (~99% of blocks)
        *(float4*)&ls[wid][l * 4] = make_float4(v0, v1, v2, v3);
        __syncthreads();
        int t = threadIdx.x;
        float sv = (ls[0][t] + ls[1][t]) + (ls[2][t] + ls[3][t]);
        atomicAdd(&sums[(size_t)gfirst * D + t], sv);
    } else {                               // graph boundary inside block (rare)
        int g = gidx[n];
        float* sg = &sums[(size_t)g * D + (size_t)l * 4];
        atomicAdd(sg + 0, v0);
        atomicAdd(sg + 1, v1);
        atomicAdd(sg + 2, v2);
        atomicAdd(sg + 3, v3);
    }
}

// pooled = sums/cnt (cnt via binary search on sorted gidx); out = pooled@fcW+fcb
__global__ __launch_bounds__(256) void k_out(const float* __restrict__ sums,
                                             const int* __restrict__ gidx,
                                             const float* __restrict__ fcW,
                                             const float* __restrict__ fcb,
                                             float* __restrict__ out) {
    __shared__ int sh[2];
    __shared__ float p[D];
    int g = blockIdx.x, t = threadIdx.x;
    if (t == 0) {
        int lo = 0, hi = N_NODES;
        while (lo < hi) { int m = (lo + hi) >> 1; if (gidx[m] < g) lo = m + 1; else hi = m; }
        sh[0] = lo;
        int lo2 = lo; hi = N_NODES;
        while (lo2 < hi) { int m = (lo2 + hi) >> 1; if (gidx[m] < g + 1) lo2 = m + 1; else hi = m; }
        sh[1] = lo2;
    }
    __syncthreads();
    float c = fmaxf((float)(sh[1] - sh[0]), 1.0f);
    p[t] = sums[(size_t)g * D + t] / c;
    __syncthreads();
    if (t < D_OUT) {
        float acc = fcb[t];
        for (int k = 0; k < D; k++)
            acc = fmaf(p[k], fcW[k * D_OUT + t], acc);
        out[g * D_OUT + t] = acc;
    }
}

extern "C" void kernel_launch(void* const* d_in, const int* in_sizes, int n_in,
                              void* d_out, int out_size, void* d_ws, size_t ws_size,
                              hipStream_t stream) {
    const float* x   = (const float*)d_in[0];
    const int*   ei  = (const int*)d_in[1];
    const float* ew  = (const float*)d_in[2];
    const int*   gix = (const int*)d_in[3];
    const float* W1  = (const float*)d_in[4];
    const float* b1  = (const float*)d_in[5];
    const float* fcW = (const float*)d_in[6];
    const float* fcb = (const float*)d_in[7];
    float* out = (float*)d_out;

    float*  ws     = (float*)d_ws;
    float*  dinv   = ws;                                  //    65,536 f
    ushort* hb     = (ushort*)(ws + 65536);               // 12.8M bf16 = 6.4M f
    int2*   edge   = (int2*)(ws + 65536 + 6400000);       //   800,000 int2
    int*    start  = (int*)(edge + N_EDGES);              //    65,536
    int*    cursor = start + 65536;                       //    65,536
    int*    partial    = cursor + 65536;                  //       256
    int*    partialExc = partial + 256;                   //       512 (pad)
    ushort* wt     = (ushort*)(partialExc + 512);         //    65,536 us
    float*  sums   = (float*)(wt + 65536);                //    32,768 f
    // total ~8.3M floats = ~33 MB

    k_init<<<NB_SCAN + 16, 256, 0, stream>>>(W1, wt, dinv, start, sums);
    k_deg_hist<<<(N_EDGES + 255) / 256, 256, 0, stream>>>(ei, ew, dinv, start);
    k_scan1<<<NB_SCAN, 256, 0, stream>>>(dinv, start, partial);
    k_scan2<<<1, 256, 0, stream>>>(partial, partialExc);
    k_scan3<<<NB_SCAN, 256, 0, stream>>>(start, cursor, partialExc);
    k_fill<<<(N_EDGES + 255) / 256, 256, 0, stream>>>(ei, ew, dinv, cursor, edge);
    k_gemm<<<(N_NODES + 63) / 64, 256, 0, stream>>>(x, wt, hb);
    k_agg<<<N_NODES / 4, 256, 0, stream>>>(start, edge, hb, dinv, b1, gix, sums);
    k_out<<<N_GRAPHS, 256, 0, stream>>>(sums, gix, fcW, fcb, out);
}

// Round 11
// 209.415 us; speedup vs baseline: 5.5317x; 1.2205x over previous
//
#include <hip/hip_runtime.h>
#include <stdint.h>

// Problem constants (match reference)
#define N_NODES  50000
#define N_EDGES  800000
#define D        256
#define D_OUT    16
#define N_GRAPHS 128
#define NB_SCAN  196        // 196*256 = 50176 >= N_NODES+1

// JAX jax_threefry_partitionable=True: bits32(i) = fold(threefry2x32((0,42),(0,i))),
// fold = o0 ^ o1; keep iff top bit == 0.  (verified round 2, absmax 0.0)

typedef short bf16x8 __attribute__((ext_vector_type(8)));
typedef float f32x4  __attribute__((ext_vector_type(4)));

__device__ __forceinline__ uint32_t rotl32(uint32_t x, int d) {
    return (x << d) | (x >> (32 - d));
}

__device__ __forceinline__ void threefry2x32(uint32_t k0, uint32_t k1,
                                             uint32_t c0, uint32_t c1,
                                             uint32_t& o0, uint32_t& o1) {
    uint32_t ks2 = k0 ^ k1 ^ 0x1BD11BDAu;
    uint32_t x0 = c0 + k0, x1 = c1 + k1;
    x0 += x1; x1 = rotl32(x1, 13); x1 ^= x0;
    x0 += x1; x1 = rotl32(x1, 15); x1 ^= x0;
    x0 += x1; x1 = rotl32(x1, 26); x1 ^= x0;
    x0 += x1; x1 = rotl32(x1, 6);  x1 ^= x0;
    x0 += k1; x1 += ks2 + 1u;
    x0 += x1; x1 = rotl32(x1, 17); x1 ^= x0;
    x0 += x1; x1 = rotl32(x1, 29); x1 ^= x0;
    x0 += x1; x1 = rotl32(x1, 16); x1 ^= x0;
    x0 += x1; x1 = rotl32(x1, 24); x1 ^= x0;
    x0 += ks2; x1 += k0 + 2u;
    x0 += x1; x1 = rotl32(x1, 13); x1 ^= x0;
    x0 += x1; x1 = rotl32(x1, 15); x1 ^= x0;
    x0 += x1; x1 = rotl32(x1, 26); x1 ^= x0;
    x0 += x1; x1 = rotl32(x1, 6);  x1 ^= x0;
    x0 += k0; x1 += k1 + 3u;
    x0 += x1; x1 = rotl32(x1, 17); x1 ^= x0;
    x0 += x1; x1 = rotl32(x1, 29); x1 ^= x0;
    x0 += x1; x1 = rotl32(x1, 16); x1 ^= x0;
    x0 += x1; x1 = rotl32(x1, 24); x1 ^= x0;
    x0 += k1; x1 += ks2 + 4u;
    x0 += x1; x1 = rotl32(x1, 13); x1 ^= x0;
    x0 += x1; x1 = rotl32(x1, 15); x1 ^= x0;
    x0 += x1; x1 = rotl32(x1, 26); x1 ^= x0;
    x0 += x1; x1 = rotl32(x1, 6);  x1 ^= x0;
    x0 += ks2; x1 += k0 + 5u;
    o0 = x0; o1 = x1;
}

__device__ __forceinline__ bool dropout_keep(uint32_t i) {
    uint32_t o0, o1;
    threefry2x32(0u, 42u, 0u, i, o0, o1);
    return ((o0 ^ o1) & 0x80000000u) == 0u;
}

__device__ __forceinline__ uint32_t bf16_rne(float f) {   // fp32 -> bf16 bits (RNE)
    uint32_t u = __float_as_uint(f);
    return (u + 0x7FFFu + ((u >> 16) & 1u)) >> 16;
}

// blocks 0..15: W[k][n] f32 -> wt[n][k] bf16 (transposed, packed)
// blocks 16..: degsum = 0 (f64), sums = 0
__global__ __launch_bounds__(256) void k_init(const float* __restrict__ W,
                                              ushort* __restrict__ wt,
                                              double* degsum, float* sums) {
    int t = threadIdx.x;
    if (blockIdx.x < 16) {
        __shared__ float td[64][65];
        int kb = blockIdx.x & 3, nb = blockIdx.x >> 2;   // 4x4 tiles of 64x64
        int nl = t & 63, r4 = t >> 6;
#pragma unroll
        for (int i = 0; i < 16; i++) {
            int kl = r4 + 4 * i;
            td[kl][nl] = W[(size_t)(kb * 64 + kl) * 256 + nb * 64 + nl];
        }
        __syncthreads();
        int kp = t & 31, nl2 = t >> 5;
        uint32_t* wt32 = (uint32_t*)wt;
#pragma unroll
        for (int i = 0; i < 8; i++) {
            int n = nl2 + 8 * i;
            uint32_t p = bf16_rne(td[2 * kp][n]) | (bf16_rne(td[2 * kp + 1][n]) << 16);
            wt32[((size_t)(nb * 64 + n) * 256 + kb * 64 + 2 * kp) >> 1] = p;
        }
    } else {
        int i = (blockIdx.x - 16) * 256 + t;
        if (i < N_NODES) degsum[i] = 0.0;
        if (i < N_GRAPHS * D) sums[i] = 0.0f;
    }
}

// ONE f64 atomic per edge: high 32 bits = count, fraction = sum of ew.
__global__ __launch_bounds__(256) void k_edeg(const int* __restrict__ ei,
                                              const float* __restrict__ ew,
                                              double* __restrict__ degsum) {
    int e = blockIdx.x * 256 + threadIdx.x;
    if (e < N_EDGES) {
        int c = ei[N_EDGES + e];
        atomicAdd(&degsum[c], 4294967296.0 + (double)ew[e]);
    }
}

// scan phase 1: degsum -> dinv + cnt(start[i]); per-block reduce of counts
__global__ __launch_bounds__(256) void k_scan1(const double* __restrict__ degsum,
                                               float* __restrict__ dinv,
                                               int* __restrict__ start,
                                               int* __restrict__ partial) {
    __shared__ int sd[256];
    int t = threadIdx.x;
    int i = blockIdx.x * 256 + t;
    int cnt = 0;
    if (i < N_NODES) {
        double val = degsum[i];
        cnt = (int)(val * (1.0 / 4294967296.0));          // exact (see analysis)
        float deg = (float)(val - (double)cnt * 4294967296.0) + 1.0f;  // +self-loop
        dinv[i] = rsqrtf(deg);                             // deg >= 1 always
        start[i] = cnt;
    }
    sd[t] = cnt;
    __syncthreads();
    for (int d = 128; d > 0; d >>= 1) {
        if (t < d) sd[t] += sd[t + d];
        __syncthreads();
    }
    if (t == 0) partial[blockIdx.x] = sd[0];
}

// scan phase 2: single block exclusive-scans the NB_SCAN partials
__global__ __launch_bounds__(256) void k_scan2(int* __restrict__ partial,
                                               int* __restrict__ partialExc) {
    __shared__ int sd[256];
    int t = threadIdx.x;
    int v = (t < NB_SCAN) ? partial[t] : 0;
    sd[t] = v;
    __syncthreads();
    for (int d = 1; d < 256; d <<= 1) {
        int u = (t >= d) ? sd[t - d] : 0;
        __syncthreads();
        sd[t] += u;
        __syncthreads();
    }
    if (t < NB_SCAN) partialExc[t] = sd[t] - v;   // exclusive
    if (t == 255) partialExc[NB_SCAN] = sd[255];  // grand total
}

// scan phase 3: per-block LDS scan + base offset -> start/cursor (coalesced)
__global__ __launch_bounds__(256) void k_scan3(int* __restrict__ start,
                                               int* __restrict__ cursor,
                                               const int* __restrict__ partialExc) {
    __shared__ int sd[256];
    int t = threadIdx.x;
    int i = blockIdx.x * 256 + t;
    int v = (i < N_NODES) ? start[i] : 0;
    sd[t] = v;
    __syncthreads();
    for (int d = 1; d < 256; d <<= 1) {
        int u = (t >= d) ? sd[t - d] : 0;
        __syncthreads();
        sd[t] += u;
        __syncthreads();
    }
    int val = partialExc[blockIdx.x] + sd[t] - v;  // exclusive prefix
    if (i < N_NODES) {
        start[i] = val;
        cursor[i] = val;
    } else if (i == N_NODES) {
        start[N_NODES] = partialExc[NB_SCAN];
    }
}

// scatter each edge's (row, RAW ew) into its CSR slot (dinv applied elsewhere)
__global__ __launch_bounds__(256) void k_fill(const int* __restrict__ ei,
                                              const float* __restrict__ ew,
                                              int* __restrict__ cursor,
                                              int2* __restrict__ edge) {
    int e = blockIdx.x * 256 + threadIdx.x;
    if (e < N_EDGES) {
        int r = ei[e];
        int c = ei[N_EDGES + e];
        int pos = atomicAdd(&cursor[c], 1);
        edge[pos] = make_int2(r, __float_as_int(ew[e]));
    }
}

// ---------------- MFMA GEMM: h'(bf16) = dinv[row] * (x @ W1) ---------------
__device__ __forceinline__ int swz(int row, int kByte) {
    return (row << 9) + (kByte ^ ((row & 7) << 4));
}

__global__ __launch_bounds__(256) void k_gemm(const float* __restrict__ x,
                                              const ushort* __restrict__ wt,
                                              const float* __restrict__ dinv,
                                              ushort* __restrict__ hb) {
    __shared__ __align__(16) char smem[65536];   // A: [0,32K), Bt: [32K,64K)
    __shared__ float sdinv[64];
    int tid = threadIdx.x;
    int Mbase = blockIdx.x * 64;

    if (tid < 64) {
        int node = Mbase + tid; if (node >= N_NODES) node = N_NODES - 1;
        sdinv[tid] = dinv[node];
    }
    // ---- stage A: x[Mbase..+63][0..255] -> bf16, swizzled ----
    const float4* xv = (const float4*)x;
#pragma unroll
    for (int i = 0; i < 16; i++) {
        int f = tid + i * 256;        // flat float4 id, 0..4095
        int r = f >> 6;               // row 0..63
        int c4 = f & 63;              // float4 index -> k = 4*c4
        int node = Mbase + r; if (node >= N_NODES) node = N_NODES - 1;
        float4 v = xv[(size_t)node * 64 + c4];
        uint32_t p0 = bf16_rne(v.x) | (bf16_rne(v.y) << 16);
        uint32_t p1 = bf16_rne(v.z) | (bf16_rne(v.w) << 16);
        *(uint2*)(smem + swz(r, c4 * 8)) = make_uint2(p0, p1);
    }

    int l = tid & 63;
    int w = tid >> 6;
    int wr = w >> 1, wc = w & 1;          // wave grid 2x2, each 32x32
    int lr = l & 15;
    int kg = l >> 4;
    int drow = (l >> 4) * 4;
    int dcol = l & 15;
    const uint4* wt4 = (const uint4*)wt;  // 16B units; 32 per 512B row

    for (int nb = 0; nb < 4; nb++) {
        // ---- stage Bt tile: wt rows nb*64..+63 (coalesced uint4 copy) ----
#pragma unroll
        for (int i = 0; i < 8; i++) {
            int f = tid + i * 256;    // 0..2047 uint4
            int r = f >> 5;           // row 0..63
            int c = f & 31;           // 16B chunk
            uint4 v = wt4[(size_t)(nb * 64 + r) * 32 + c];
            *(uint4*)(smem + 32768 + swz(r, c * 16)) = v;
        }
        __syncthreads();

        f32x4 acc00 = {0.f, 0.f, 0.f, 0.f};
        f32x4 acc01 = acc00, acc10 = acc00, acc11 = acc00;
#pragma unroll
        for (int ks = 0; ks < 8; ks++) {
            int kB = ks * 64 + kg * 16;
            bf16x8 a0 = *(const bf16x8*)(smem + swz(wr * 32 + lr, kB));
            bf16x8 a1 = *(const bf16x8*)(smem + swz(wr * 32 + 16 + lr, kB));
            bf16x8 b0 = *(const bf16x8*)(smem + 32768 + swz(wc * 32 + lr, kB));
            bf16x8 b1 = *(const bf16x8*)(smem + 32768 + swz(wc * 32 + 16 + lr, kB));
            acc00 = __builtin_amdgcn_mfma_f32_16x16x32_bf16(a0, b0, acc00, 0, 0, 0);
            acc01 = __builtin_amdgcn_mfma_f32_16x16x32_bf16(a0, b1, acc01, 0, 0, 0);
            acc10 = __builtin_amdgcn_mfma_f32_16x16x32_bf16(a1, b0, acc10, 0, 0, 0);
            acc11 = __builtin_amdgcn_mfma_f32_16x16x32_bf16(a1, b1, acc11, 0, 0, 0);
        }
        // D layout: row=(l>>4)*4+r, col=l&15  (m89-verified); scale by dinv[row]
        int c0 = nb * 64 + wc * 32 + dcol;
#pragma unroll
        for (int r = 0; r < 4; r++) {
            int lr0 = wr * 32 + drow + r;
            int n0 = Mbase + lr0;
            int n1 = n0 + 16;
            float s0 = sdinv[lr0], s1 = sdinv[lr0 + 16];
            if (n0 < N_NODES) {
                hb[(size_t)n0 * 256 + c0]      = (ushort)bf16_rne(acc00[r] * s0);
                hb[(size_t)n0 * 256 + c0 + 16] = (ushort)bf16_rne(acc01[r] * s0);
            }
            if (n1 < N_NODES) {
                hb[(size_t)n1 * 256 + c0]      = (ushort)bf16_rne(acc10[r] * s1);
                hb[(size_t)n1 * 256 + c0 + 16] = (ushort)bf16_rne(acc11[r] * s1);
            }
        }
        __syncthreads();   // Bt reused next iter
    }
}

// CSR aggregate: 2 edges per wave-step (lanes 0-31 edge j, 32-63 edge j+1,
// 16B/lane gathers), then dinv[n]*(sum + h'[n]) + bias, ReLU, dropout,
// block-level LDS pool flush.
__device__ __forceinline__ void fma8(float* a, uint4 u, float w) {
    uint32_t p;
    p = u.x;
    a[0] = fmaf(w, __uint_as_float(p << 16), a[0]);
    a[1] = fmaf(w, __uint_as_float(p & 0xffff0000u), a[1]);
    p = u.y;
    a[2] = fmaf(w, __uint_as_float(p << 16), a[2]);
    a[3] = fmaf(w, __uint_as_float(p & 0xffff0000u), a[3]);
    p = u.z;
    a[4] = fmaf(w, __uint_as_float(p << 16), a[4]);
    a[5] = fmaf(w, __uint_as_float(p & 0xffff0000u), a[5]);
    p = u.w;
    a[6] = fmaf(w, __uint_as_float(p << 16), a[6]);
    a[7] = fmaf(w, __uint_as_float(p & 0xffff0000u), a[7]);
}

__global__ __launch_bounds__(256) void k_agg(const int* __restrict__ start,
                                             const int2* __restrict__ edge,
                                             const ushort* __restrict__ hb,
                                             const float* __restrict__ dinv,
                                             const float* __restrict__ b1,
                                             const int* __restrict__ gidx,
                                             float* __restrict__ sums) {
    __shared__ float ls[4][256];
    int wid = threadIdx.x >> 6;
    int l = threadIdx.x & 63;
    int half = l >> 5;                     // 0: edge j, 1: edge j+1
    int cl = l & 31;                       // 16B column chunk (cols 8cl..8cl+7)
    int n = blockIdx.x * 4 + wid;          // always < N_NODES
    const uint4* h16 = (const uint4*)hb;   // 32 uint4 per 512B row
    int s = start[n], e = start[n + 1];

    float a0[8] = {0,0,0,0,0,0,0,0}, a1[8] = {0,0,0,0,0,0,0,0};
    float a2[8] = {0,0,0,0,0,0,0,0}, a3[8] = {0,0,0,0,0,0,0,0};
    int j = s;
    for (; j + 8 <= e; j += 8) {
        int2 e0 = edge[j + 0 + half];
        int2 e1 = edge[j + 2 + half];
        int2 e2 = edge[j + 4 + half];
        int2 e3 = edge[j + 6 + half];
        uint4 u0 = h16[(size_t)e0.x * 32 + cl];
        uint4 u1 = h16[(size_t)e1.x * 32 + cl];
        uint4 u2 = h16[(size_t)e2.x * 32 + cl];
        uint4 u3 = h16[(size_t)e3.x * 32 + cl];
        fma8(a0, u0, __int_as_float(e0.y));
        fma8(a1, u1, __int_as_float(e1.y));
        fma8(a2, u2, __int_as_float(e2.y));
        fma8(a3, u3, __int_as_float(e3.y));
    }
    for (; j + 2 <= e; j += 2) {
        int2 ee = edge[j + half];
        uint4 u = h16[(size_t)ee.x * 32 + cl];
        fma8(a0, u, __int_as_float(ee.y));
    }
    if (j < e) {                           // odd remainder: half1 contributes 0
        int2 ee = edge[j];
        uint4 u = h16[(size_t)ee.x * 32 + cl];
        float w = half ? 0.0f : __int_as_float(ee.y);
        fma8(a0, u, w);
    }
    float full[8];
#pragma unroll
    for (int k = 0; k < 8; k++)
        full[k] = (a0[k] + a1[k]) + (a2[k] + a3[k]);
#pragma unroll
    for (int k = 0; k < 8; k++)
        full[k] += __shfl_xor(full[k], 32, 64);   // combine the two edge-halves

    // self-loop + bias + relu + dropout for this lane's 4 cols: 8cl+4*half+..
    float dn = dinv[n];
    uint4 un = h16[(size_t)n * 32 + cl];
    uint32_t q0 = half ? un.z : un.x;
    uint32_t q1 = half ? un.w : un.y;
    float hn0 = __uint_as_float(q0 << 16);
    float hn1 = __uint_as_float(q0 & 0xffff0000u);
    float hn2 = __uint_as_float(q1 << 16);
    float hn3 = __uint_as_float(q1 & 0xffff0000u);
    int off = 4 * half;
    int col = 8 * cl + off;
    float4 bv = ((const float4*)b1)[2 * cl + half];
    float v0 = fmaxf(dn * (full[off + 0] + hn0) + bv.x, 0.f);
    float v1 = fmaxf(dn * (full[off + 1] + hn1) + bv.y, 0.f);
    float v2 = fmaxf(dn * (full[off + 2] + hn2) + bv.z, 0.f);
    float v3 = fmaxf(dn * (full[off + 3] + hn3) + bv.w, 0.f);
    uint32_t base = (uint32_t)n * D + (uint32_t)col;
    v0 = dropout_keep(base + 0u) ? v0 * 2.f : 0.f;
    v1 = dropout_keep(base + 1u) ? v1 * 2.f : 0.f;
    v2 = dropout_keep(base + 2u) ? v2 * 2.f : 0.f;
    v3 = dropout_keep(base + 3u) ? v3 * 2.f : 0.f;

    int gfirst = gidx[blockIdx.x * 4];
    int glast  = gidx[blockIdx.x * 4 + 3];
    if (gfirst == glast) {                 // block-uniform branch (~99% of blocks)
        *(float4*)&ls[wid][col] = make_float4(v0, v1, v2, v3);
        __syncthreads();
        int t = threadIdx.x;
        float sv = (ls[0][t] + ls[1][t]) + (ls[2][t] + ls[3][t]);
        atomicAdd(&sums[(size_t)gfirst * D + t], sv);
    } else {                               // graph boundary inside block (rare)
        int g = gidx[n];
        float* sg = &sums[(size_t)g * D + col];
        atomicAdd(sg + 0, v0);
        atomicAdd(sg + 1, v1);
        atomicAdd(sg + 2, v2);
        atomicAdd(sg + 3, v3);
    }
}

// pooled = sums/cnt (cnt via binary search on sorted gidx); out = pooled@fcW+fcb
__global__ __launch_bounds__(256) void k_out(const float* __restrict__ sums,
                                             const int* __restrict__ gidx,
                                             const float* __restrict__ fcW,
                                             const float* __restrict__ fcb,
                                             float* __restrict__ out) {
    __shared__ int sh[2];
    __shared__ float p[D];
    int g = blockIdx.x, t = threadIdx.x;
    if (t == 0) {
        int lo = 0, hi = N_NODES;
        while (lo < hi) { int m = (lo + hi) >> 1; if (gidx[m] < g) lo = m + 1; else hi = m; }
        sh[0] = lo;
        int lo2 = lo; hi = N_NODES;
        while (lo2 < hi) { int m = (lo2 + hi) >> 1; if (gidx[m] < g + 1) lo2 = m + 1; else hi = m; }
        sh[1] = lo2;
    }
    __syncthreads();
    float c = fmaxf((float)(sh[1] - sh[0]), 1.0f);
    p[t] = sums[(size_t)g * D + t] / c;
    __syncthreads();
    if (t < D_OUT) {
        float acc = fcb[t];
        for (int k = 0; k < D; k++)
            acc = fmaf(p[k], fcW[k * D_OUT + t], acc);
        out[g * D_OUT + t] = acc;
    }
}

extern "C" void kernel_launch(void* const* d_in, const int* in_sizes, int n_in,
                              void* d_out, int out_size, void* d_ws, size_t ws_size,
                              hipStream_t stream) {
    const float* x   = (const float*)d_in[0];
    const int*   ei  = (const int*)d_in[1];
    const float* ew  = (const float*)d_in[2];
    const int*   gix = (const int*)d_in[3];
    const float* W1  = (const float*)d_in[4];
    const float* b1  = (const float*)d_in[5];
    const float* fcW = (const float*)d_in[6];
    const float* fcb = (const float*)d_in[7];
    float* out = (float*)d_out;

    float*  ws     = (float*)d_ws;
    float*  dinv   = ws;                                  //    65,536 f
    ushort* hb     = (ushort*)(ws + 65536);               // 12.8M bf16 = 6.4M f
    int2*   edge   = (int2*)(ws + 65536 + 6400000);       //   800,000 int2
    int*    start  = (int*)(edge + N_EDGES);              //    65,536
    int*    cursor = start + 65536;                       //    65,536
    int*    partial    = cursor + 65536;                  //       256
    int*    partialExc = partial + 256;                   //       512 (pad)
    ushort* wt     = (ushort*)(partialExc + 512);         //    65,536 us
    float*  sums   = (float*)(wt + 65536);                //    32,768 f
    double* degsum = (double*)(sums + 32768);             //    50,000 f64
    // total ~8.4M floats = ~34 MB

    k_init<<<NB_SCAN + 16, 256, 0, stream>>>(W1, wt, degsum, sums);
    k_edeg<<<(N_EDGES + 255) / 256, 256, 0, stream>>>(ei, ew, degsum);
    k_scan1<<<NB_SCAN, 256, 0, stream>>>(degsum, dinv, start, partial);
    k_scan2<<<1, 256, 0, stream>>>(partial, partialExc);
    k_scan3<<<NB_SCAN, 256, 0, stream>>>(start, cursor, partialExc);
    k_fill<<<(N_EDGES + 255) / 256, 256, 0, stream>>>(ei, ew, cursor, edge);
    k_gemm<<<(N_NODES + 63) / 64, 256, 0, stream>>>(x, wt, dinv, hb);
    k_agg<<<N_NODES / 4, 256, 0, stream>>>(start, edge, hb, dinv, b1, gix, sums);
    k_out<<<N_GRAPHS, 256, 0, stream>>>(sums, gix, fcW, fcb, out);
}